// Round 4
// baseline (2379.180 us; speedup 1.0000x reference)
//
#include <hip/hip_runtime.h>
#include <hip/hip_bf16.h>

#define LSEQ 2048
#define DMODEL 2048
#define DINNER 4096
#define DSTATE 16
#define DTRANK 128
#define DCONV 4
#define DXP (DTRANK + 2*DSTATE)   // 160

using bf16 = __hip_bfloat16;
typedef __attribute__((ext_vector_type(8))) short short8;
typedef __attribute__((ext_vector_type(4))) float float4v;

__device__ __forceinline__ float b2f(bf16 v) { return __bfloat162float(v); }
__device__ __forceinline__ bf16 f2b(float v) { return __float2bfloat16(v); }
__device__ __forceinline__ float bl16(unsigned u) { return __uint_as_float(u << 16); }
__device__ __forceinline__ float bh16(unsigned u) { return __uint_as_float(u & 0xffff0000u); }

__device__ __forceinline__ short f2bs(float v) {
    bf16 b = __float2bfloat16(v);
    union { bf16 b; short s; } u; u.b = b; return u.s;
}

// load 8 contiguous elements as 8 packed bf16 (for MFMA fragments / LDS staging)
__device__ __forceinline__ short8 ld8(const float* p) {
    float4v f0 = *(const float4v*)p;
    float4v f1 = *(const float4v*)(p + 4);
    short8 r;
    r[0] = f2bs(f0[0]); r[1] = f2bs(f0[1]); r[2] = f2bs(f0[2]); r[3] = f2bs(f0[3]);
    r[4] = f2bs(f1[0]); r[5] = f2bs(f1[1]); r[6] = f2bs(f1[2]); r[7] = f2bs(f1[3]);
    return r;
}
__device__ __forceinline__ short8 ld8(const bf16* p) { return *(const short8*)p; }

template<typename CT> __device__ __forceinline__ CT cvtC(float v);
template<> __device__ __forceinline__ bf16  cvtC<bf16>(float v)  { return f2b(v); }
template<> __device__ __forceinline__ float cvtC<float>(float v) { return v; }

// C[m][n] = sum_k A[m][k] * B[n][k].  A: fp32 or bf16; B: fp32 (weights);
// C: bf16 or fp32.  SP: softplus(acc + bias[n]) epilogue (dt_proj).
// 64x64 tile, BK=32, 4 waves x (2x2 mfma_f32_16x16x32_bf16), fp32 accumulate.
template<typename AT, typename CT, bool SP>
__global__ __launch_bounds__(256) void gemm_bt(
    const AT* __restrict__ A, int lda,
    const float* __restrict__ B, int ldb,
    CT* __restrict__ C, int ldc,
    int M, int N, int K,
    const float* __restrict__ bias)
{
    // +8 bf16 pad -> 80B row stride: 16B-aligned rows, 2-way bank alias only (free)
    __shared__ bf16 As[64][40];
    __shared__ bf16 Bs[64][40];

    const int t    = threadIdx.x;
    const int bm0  = blockIdx.x * 64;
    const int bn0  = blockIdx.y * 64;
    const int row  = t >> 2;          // 0..63
    const int seg  = (t & 3) * 8;     // 0,8,16,24
    const int wave = t >> 6;          // 0..3
    const int lane = t & 63;
    const int wm   = (wave >> 1) * 32;
    const int wn   = (wave & 1) * 32;
    const int t16  = lane & 15;
    const int quad = lane >> 4;

    float4v acc[2][2];
#pragma unroll
    for (int i = 0; i < 2; i++)
#pragma unroll
        for (int j = 0; j < 2; j++) acc[i][j] = (float4v)(0.0f);

    const AT*    Aptr = A + (size_t)(bm0 + row) * lda + seg;
    const float* Bptr = B + (size_t)(bn0 + row) * ldb + seg;
    const bool a_ok = (bm0 + row) < M;
    const bool b_ok = (bn0 + row) < N;
    const short8 zero8 = (short8)(0);

    for (int k0 = 0; k0 < K; k0 += 32) {
        short8 av = a_ok ? ld8(Aptr + k0) : zero8;
        short8 bv = b_ok ? ld8(Bptr + k0) : zero8;
        __syncthreads();                 // protect LDS from previous iter's readers
        *(short8*)(&As[row][seg]) = av;
        *(short8*)(&Bs[row][seg]) = bv;
        __syncthreads();

        short8 a0 = *(const short8*)(&As[wm + t16][quad * 8]);
        short8 a1 = *(const short8*)(&As[wm + 16 + t16][quad * 8]);
        short8 b0 = *(const short8*)(&Bs[wn + t16][quad * 8]);
        short8 b1 = *(const short8*)(&Bs[wn + 16 + t16][quad * 8]);
        acc[0][0] = __builtin_amdgcn_mfma_f32_16x16x32_bf16(a0, b0, acc[0][0], 0, 0, 0);
        acc[0][1] = __builtin_amdgcn_mfma_f32_16x16x32_bf16(a0, b1, acc[0][1], 0, 0, 0);
        acc[1][0] = __builtin_amdgcn_mfma_f32_16x16x32_bf16(a1, b0, acc[1][0], 0, 0, 0);
        acc[1][1] = __builtin_amdgcn_mfma_f32_16x16x32_bf16(a1, b1, acc[1][1], 0, 0, 0);
    }

#pragma unroll
    for (int i = 0; i < 2; i++) {
#pragma unroll
        for (int j = 0; j < 2; j++) {
            int n_g = bn0 + wn + j * 16 + t16;
            if (n_g >= N) continue;
            float bia = SP ? bias[n_g] : 0.0f;
#pragma unroll
            for (int r = 0; r < 4; r++) {
                int m_g = bm0 + wm + i * 16 + quad * 4 + r;
                if (m_g >= M) continue;
                float v = acc[i][j][r];
                if (SP) {
                    float x = v + bia;
                    v = (x > 20.0f) ? x : log1pf(__expf(x));  // softplus
                }
                C[(size_t)m_g * ldc + n_g] = cvtC<CT>(v);
            }
        }
    }
}

// depthwise causal conv (K=4) + SiLU, IN-PLACE on the x-half of xz (bf16).
// One thread owns one channel d for the entire sequence; the 3-tap history
// lives in registers, so overwriting xz[l][d] never clobbers a needed input.
__global__ __launch_bounds__(256) void conv_silu_inplace(
    bf16* __restrict__ xz, const float* __restrict__ w)
{
    const int d = blockIdx.x * 256 + threadIdx.x;   // 0..DINNER-1
    const float w0 = w[d * 4 + 0];
    const float w1 = w[d * 4 + 1];
    const float w2 = w[d * 4 + 2];
    const float w3 = w[d * 4 + 3];
    bf16* p = xz + d;
    const size_t S = 2 * DINNER;
    float xm3 = 0.f, xm2 = 0.f, xm1 = 0.f;
    for (int l = 0; l < LSEQ; l += 4) {
        float x0 = b2f(p[(size_t)(l + 0) * S]);
        float x1 = b2f(p[(size_t)(l + 1) * S]);
        float x2 = b2f(p[(size_t)(l + 2) * S]);
        float x3 = b2f(p[(size_t)(l + 3) * S]);
        float a0 = w0 * xm3 + w1 * xm2 + w2 * xm1 + w3 * x0;
        float a1 = w0 * xm2 + w1 * xm1 + w2 * x0  + w3 * x1;
        float a2 = w0 * xm1 + w1 * x0  + w2 * x1  + w3 * x2;
        float a3 = w0 * x0  + w1 * x1  + w2 * x2  + w3 * x3;
        p[(size_t)(l + 0) * S] = f2b(a0 / (1.0f + __expf(-a0)));
        p[(size_t)(l + 1) * S] = f2b(a1 / (1.0f + __expf(-a1)));
        p[(size_t)(l + 2) * S] = f2b(a2 / (1.0f + __expf(-a2)));
        p[(size_t)(l + 3) * S] = f2b(a3 / (1.0f + __expf(-a3)));
        xm3 = x1; xm2 = x2; xm1 = x3;
    }
}

template<typename T> __device__ __forceinline__ float cvtL(T v);
template<> __device__ __forceinline__ float cvtL<bf16>(bf16 v)   { return b2f(v); }
template<> __device__ __forceinline__ float cvtL<float>(float v) { return v; }

// Selective scan. thread = (d, nq) with nq owning 4 of the 16 states.
// 256 threads/block = 64 channels; grid 64 blocks covers DINNER=4096.
// u = xz[l][d] (conv'd x); z = xz[l][DINNER+d]; y overwrites the z slot.
template<typename DT>
__global__ __launch_bounds__(256) void scan_kernel(
    const DT* __restrict__ dlt, bf16* __restrict__ xz,
    const bf16* __restrict__ xdbl,
    const float* __restrict__ A_log, const float* __restrict__ Dp)
{
    const int nq = threadIdx.x & 3;
    const int d  = blockIdx.x * 64 + (threadIdx.x >> 2);

    float Ac[4];
#pragma unroll
    for (int i = 0; i < 4; i++)
        Ac[i] = -__expf(A_log[d * DSTATE + nq * 4 + i]);
    const float Dv = Dp[d];

    float h[4] = {0.f, 0.f, 0.f, 0.f};
    for (int l = 0; l < LSEQ; ++l) {
        const float delta = cvtL<DT>(dlt[(size_t)l * DINNER + d]);
        const float u     = b2f(xz[(size_t)l * (2 * DINNER) + d]);
        // B chunk (4 bf16) and C chunk for this nq: contiguous 8B each
        const uint2 qb = *(const uint2*)(xdbl + (size_t)l * DXP + DTRANK + nq * 4);
        const uint2 qc = *(const uint2*)(xdbl + (size_t)l * DXP + DTRANK + DSTATE + nq * 4);
        float Bv[4] = { bl16(qb.x), bh16(qb.x), bl16(qb.y), bh16(qb.y) };
        float Cv[4] = { bl16(qc.x), bh16(qc.x), bl16(qc.y), bh16(qc.y) };
        const float du = delta * u;
        float yv = 0.f;
#pragma unroll
        for (int i = 0; i < 4; i++) {
            float dA = __expf(delta * Ac[i]);
            h[i] = h[i] * dA + du * Bv[i];
            yv += h[i] * Cv[i];
        }
        // reduce across the 4 nq lanes (lanes d*4 .. d*4+3)
        yv += __shfl_xor(yv, 1);
        yv += __shfl_xor(yv, 2);
        if (nq == 0) {
            yv += u * Dv;
            bf16* zp = xz + (size_t)l * (2 * DINNER) + DINNER + d;
            float z = b2f(*zp);
            yv *= z / (1.0f + __expf(-z));        // silu(z) gate
            *zp = f2b(yv);                        // y overwrites z slot
        }
    }
}

extern "C" void kernel_launch(void* const* d_in, const int* in_sizes, int n_in,
                              void* d_out, int out_size, void* d_ws, size_t ws_size,
                              hipStream_t stream)
{
    // Inputs are FLOAT32 (reference dtypes), in setup_inputs() DICT order:
    //   0 hidden_states (1,L,DM)      1 in_proj_weight (2*DI,DM)
    //   2 conv1d_weight (DI,1,4)      3 x_proj_weight (160,DI)
    //   4 dt_proj_weight (DI,128)     5 out_proj_weight (DM,DI)   <-- in dict literal
    //   6 dt_proj_bias (DI,)          7 A_log (DI,16)             <-- appended after
    //   8 D (DI,)
    const float* hs      = (const float*)d_in[0];
    const float* w_in    = (const float*)d_in[1];
    const float* w_conv  = (const float*)d_in[2];
    const float* w_xproj = (const float*)d_in[3];
    const float* w_dt    = (const float*)d_in[4];
    const float *w_out, *b_dt, *A_log, *Dp;
    if (in_sizes[5] == DMODEL * DINNER) {        // dict order (expected)
        w_out = (const float*)d_in[5];
        b_dt  = (const float*)d_in[6];
        A_log = (const float*)d_in[7];
        Dp    = (const float*)d_in[8];
    } else {                                     // fallback: signature order
        b_dt  = (const float*)d_in[5];
        A_log = (const float*)d_in[6];
        Dp    = (const float*)d_in[7];
        w_out = (const float*)d_in[8];
    }
    float* out = (float*)d_out;

    // scratch: xz + xdbl always bf16; dlt fp32 if workspace allows (accuracy:
    // delta sits in an exponent in the scan), else bf16.
    bf16* xz   = (bf16*)d_ws;                      // [L][2*DI]  33.5 MB
    bf16* xdbl = xz + (size_t)LSEQ * 2 * DINNER;   // [L][160]    0.7 MB
    char* tail = (char*)(xdbl + (size_t)LSEQ * DXP);
    size_t used = (size_t)(tail - (char*)d_ws);
    bool dlt_f32 = (ws_size - used) >= (size_t)LSEQ * DINNER * sizeof(float);

    dim3 blk(256);

    // 1) xz[l][e] = sum_d hs[l][d] * w_in[e][d]
    gemm_bt<float, bf16, false><<<dim3(LSEQ / 64, (2 * DINNER) / 64), blk, 0, stream>>>(
        hs, DMODEL, w_in, DMODEL, xz, 2 * DINNER, LSEQ, 2 * DINNER, DMODEL, nullptr);

    // 2) depthwise conv + silu, in place on x-half of xz
    conv_silu_inplace<<<dim3(DINNER / 256), blk, 0, stream>>>(xz, w_conv);

    // 3) xdbl[l][p] = sum_d x[l][d] * w_xproj[p][d]   (A = x-half of xz, lda=8192)
    gemm_bt<bf16, bf16, false><<<dim3(LSEQ / 64, 3), blk, 0, stream>>>(
        xz, 2 * DINNER, w_xproj, DINNER, xdbl, DXP, LSEQ, DXP, DINNER, nullptr);

    // 4) dlt[l][d] = softplus(sum_r xdbl[l][r] * w_dt[d][r] + bias[d])
    // 5) selective scan + u*D + silu(z) gate; y overwrites z-half of xz
    if (dlt_f32) {
        float* dlt = (float*)tail;
        gemm_bt<bf16, float, true><<<dim3(LSEQ / 64, DINNER / 64), blk, 0, stream>>>(
            xdbl, DXP, w_dt, DTRANK, dlt, DINNER, LSEQ, DINNER, DTRANK, b_dt);
        scan_kernel<float><<<dim3(DINNER / 64), blk, 0, stream>>>(dlt, xz, xdbl, A_log, Dp);
    } else {
        bf16* dlt = (bf16*)tail;
        gemm_bt<bf16, bf16, true><<<dim3(LSEQ / 64, DINNER / 64), blk, 0, stream>>>(
            xdbl, DXP, w_dt, DTRANK, dlt, DINNER, LSEQ, DINNER, DTRANK, b_dt);
        scan_kernel<bf16><<<dim3(DINNER / 64), blk, 0, stream>>>(dlt, xz, xdbl, A_log, Dp);
    }

    // 6) out[l][m] = sum_d y[l][d] * w_out[m][d]   (A = z-half of xz, lda=8192)
    gemm_bt<bf16, float, false><<<dim3(LSEQ / 64, DMODEL / 64), blk, 0, stream>>>(
        xz + DINNER, 2 * DINNER, w_out, DINNER, out, DMODEL, LSEQ, DMODEL, DINNER, nullptr);
}

// Round 5
// 737.468 us; speedup vs baseline: 3.2261x; 3.2261x over previous
//
#include <hip/hip_runtime.h>
#include <hip/hip_bf16.h>

#define LSEQ 2048
#define DMODEL 2048
#define DINNER 4096
#define DSTATE 16
#define DTRANK 128
#define DCONV 4
#define DXP (DTRANK + 2*DSTATE)   // 160
#define NCHUNK 64
#define LCHUNK (LSEQ / NCHUNK)    // 32

using bf16 = __hip_bfloat16;
typedef __attribute__((ext_vector_type(8))) short short8;
typedef __attribute__((ext_vector_type(4))) float float4v;

__device__ __forceinline__ float b2f(bf16 v) { return __bfloat162float(v); }
__device__ __forceinline__ bf16 f2b(float v) { return __float2bfloat16(v); }
__device__ __forceinline__ float bl16(unsigned u) { return __uint_as_float(u << 16); }
__device__ __forceinline__ float bh16(unsigned u) { return __uint_as_float(u & 0xffff0000u); }

__device__ __forceinline__ short f2bs(float v) {
    bf16 b = __float2bfloat16(v);
    union { bf16 b; short s; } u; u.b = b; return u.s;
}

// load 8 contiguous elements as 8 packed bf16 (for MFMA fragments / LDS staging)
__device__ __forceinline__ short8 ld8(const float* p) {
    float4v f0 = *(const float4v*)p;
    float4v f1 = *(const float4v*)(p + 4);
    short8 r;
    r[0] = f2bs(f0[0]); r[1] = f2bs(f0[1]); r[2] = f2bs(f0[2]); r[3] = f2bs(f0[3]);
    r[4] = f2bs(f1[0]); r[5] = f2bs(f1[1]); r[6] = f2bs(f1[2]); r[7] = f2bs(f1[3]);
    return r;
}
__device__ __forceinline__ short8 ld8(const bf16* p) { return *(const short8*)p; }

template<typename CT> __device__ __forceinline__ CT cvtC(float v);
template<> __device__ __forceinline__ bf16  cvtC<bf16>(float v)  { return f2b(v); }
template<> __device__ __forceinline__ float cvtC<float>(float v) { return v; }

template<typename T> __device__ __forceinline__ float cvtL(T v);
template<> __device__ __forceinline__ float cvtL<bf16>(bf16 v)   { return b2f(v); }
template<> __device__ __forceinline__ float cvtL<float>(float v) { return v; }

// C[m][n] = sum_k A[m][k] * B[n][k].  A: fp32 or bf16; B: fp32 (weights);
// C: bf16 or fp32.  SP: softplus(acc + bias[n]) epilogue (dt_proj).
// 64x64 tile, BK=32, 4 waves x (2x2 mfma_f32_16x16x32_bf16), fp32 accumulate.
template<typename AT, typename CT, bool SP>
__global__ __launch_bounds__(256) void gemm_bt(
    const AT* __restrict__ A, int lda,
    const float* __restrict__ B, int ldb,
    CT* __restrict__ C, int ldc,
    int M, int N, int K,
    const float* __restrict__ bias)
{
    __shared__ bf16 As[64][40];
    __shared__ bf16 Bs[64][40];

    const int t    = threadIdx.x;
    const int bm0  = blockIdx.x * 64;
    const int bn0  = blockIdx.y * 64;
    const int row  = t >> 2;
    const int seg  = (t & 3) * 8;
    const int wave = t >> 6;
    const int lane = t & 63;
    const int wm   = (wave >> 1) * 32;
    const int wn   = (wave & 1) * 32;
    const int t16  = lane & 15;
    const int quad = lane >> 4;

    float4v acc[2][2];
#pragma unroll
    for (int i = 0; i < 2; i++)
#pragma unroll
        for (int j = 0; j < 2; j++) acc[i][j] = (float4v)(0.0f);

    const AT*    Aptr = A + (size_t)(bm0 + row) * lda + seg;
    const float* Bptr = B + (size_t)(bn0 + row) * ldb + seg;
    const bool a_ok = (bm0 + row) < M;
    const bool b_ok = (bn0 + row) < N;
    const short8 zero8 = (short8)(0);

    for (int k0 = 0; k0 < K; k0 += 32) {
        short8 av = a_ok ? ld8(Aptr + k0) : zero8;
        short8 bv = b_ok ? ld8(Bptr + k0) : zero8;
        __syncthreads();
        *(short8*)(&As[row][seg]) = av;
        *(short8*)(&Bs[row][seg]) = bv;
        __syncthreads();

        short8 a0 = *(const short8*)(&As[wm + t16][quad * 8]);
        short8 a1 = *(const short8*)(&As[wm + 16 + t16][quad * 8]);
        short8 b0 = *(const short8*)(&Bs[wn + t16][quad * 8]);
        short8 b1 = *(const short8*)(&Bs[wn + 16 + t16][quad * 8]);
        acc[0][0] = __builtin_amdgcn_mfma_f32_16x16x32_bf16(a0, b0, acc[0][0], 0, 0, 0);
        acc[0][1] = __builtin_amdgcn_mfma_f32_16x16x32_bf16(a0, b1, acc[0][1], 0, 0, 0);
        acc[1][0] = __builtin_amdgcn_mfma_f32_16x16x32_bf16(a1, b0, acc[1][0], 0, 0, 0);
        acc[1][1] = __builtin_amdgcn_mfma_f32_16x16x32_bf16(a1, b1, acc[1][1], 0, 0, 0);
    }

#pragma unroll
    for (int i = 0; i < 2; i++) {
#pragma unroll
        for (int j = 0; j < 2; j++) {
            int n_g = bn0 + wn + j * 16 + t16;
            if (n_g >= N) continue;
            float bia = SP ? bias[n_g] : 0.0f;
#pragma unroll
            for (int r = 0; r < 4; r++) {
                int m_g = bm0 + wm + i * 16 + quad * 4 + r;
                if (m_g >= M) continue;
                float v = acc[i][j][r];
                if (SP) {
                    float x = v + bia;
                    v = (x > 20.0f) ? x : log1pf(__expf(x));
                }
                C[(size_t)m_g * ldc + n_g] = cvtC<CT>(v);
            }
        }
    }
}

// ---- conv, L-parallel: reads xz (x-half), writes xc. No in-place hazard. ----
__global__ __launch_bounds__(256) void conv_silu_par(
    const bf16* __restrict__ xz, const float* __restrict__ w, bf16* __restrict__ xc)
{
    const int d  = blockIdx.x * 256 + threadIdx.x;
    const int lc = blockIdx.y * 256;
    const float w0 = w[d * 4 + 0];
    const float w1 = w[d * 4 + 1];
    const float w2 = w[d * 4 + 2];
    const float w3 = w[d * 4 + 3];
    const size_t S = 2 * DINNER;
    const bf16* p = xz + d;
    float xm3 = 0.f, xm2 = 0.f, xm1 = 0.f;
    if (lc >= 3) {
        xm3 = b2f(p[(size_t)(lc - 3) * S]);
        xm2 = b2f(p[(size_t)(lc - 2) * S]);
        xm1 = b2f(p[(size_t)(lc - 1) * S]);
    }
    for (int l = lc; l < lc + 256; ++l) {
        float x0 = b2f(p[(size_t)l * S]);
        float a = w0 * xm3 + w1 * xm2 + w2 * xm1 + w3 * x0;
        xc[(size_t)l * DINNER + d] = f2b(a / (1.0f + __expf(-a)));
        xm3 = xm2; xm2 = xm1; xm1 = x0;
    }
}

// ---- conv, serial in-place fallback (one thread per channel) ----
__global__ __launch_bounds__(256) void conv_silu_inplace(
    bf16* __restrict__ xz, const float* __restrict__ w)
{
    const int d = blockIdx.x * 256 + threadIdx.x;
    const float w0 = w[d * 4 + 0];
    const float w1 = w[d * 4 + 1];
    const float w2 = w[d * 4 + 2];
    const float w3 = w[d * 4 + 3];
    bf16* p = xz + d;
    const size_t S = 2 * DINNER;
    float xm3 = 0.f, xm2 = 0.f, xm1 = 0.f;
    for (int l = 0; l < LSEQ; l += 4) {
        float x0 = b2f(p[(size_t)(l + 0) * S]);
        float x1 = b2f(p[(size_t)(l + 1) * S]);
        float x2 = b2f(p[(size_t)(l + 2) * S]);
        float x3 = b2f(p[(size_t)(l + 3) * S]);
        float a0 = w0 * xm3 + w1 * xm2 + w2 * xm1 + w3 * x0;
        float a1 = w0 * xm2 + w1 * xm1 + w2 * x0  + w3 * x1;
        float a2 = w0 * xm1 + w1 * x0  + w2 * x1  + w3 * x2;
        float a3 = w0 * x0  + w1 * x1  + w2 * x2  + w3 * x3;
        p[(size_t)(l + 0) * S] = f2b(a0 / (1.0f + __expf(-a0)));
        p[(size_t)(l + 1) * S] = f2b(a1 / (1.0f + __expf(-a1)));
        p[(size_t)(l + 2) * S] = f2b(a2 / (1.0f + __expf(-a2)));
        p[(size_t)(l + 3) * S] = f2b(a3 / (1.0f + __expf(-a3)));
        xm3 = x1; xm2 = x2; xm1 = x3;
    }
}

// ---- chunked scan pass 1: local scan from h=0; emit end-state + decay prod ----
// thread = (d, nq); block = 64 channels; grid = (DINNER/64, NCHUNK)
__global__ __launch_bounds__(256) void scan_chunk1(
    const float* __restrict__ dlt, const bf16* __restrict__ xc,
    const bf16* __restrict__ xdbl, const float* __restrict__ A_log,
    float* __restrict__ hend, float* __restrict__ Pbuf)
{
    const int nq = threadIdx.x & 3;
    const int d  = blockIdx.x * 64 + (threadIdx.x >> 2);
    const int c  = blockIdx.y;

    float Ac[4];
#pragma unroll
    for (int i = 0; i < 4; i++)
        Ac[i] = -__expf(A_log[d * DSTATE + nq * 4 + i]);

    float h[4] = {0.f, 0.f, 0.f, 0.f};
    float P[4] = {1.f, 1.f, 1.f, 1.f};
    for (int l = c * LCHUNK; l < (c + 1) * LCHUNK; ++l) {
        const float delta = dlt[(size_t)l * DINNER + d];
        const float u     = b2f(xc[(size_t)l * DINNER + d]);
        const uint2 qb = *(const uint2*)(xdbl + (size_t)l * DXP + DTRANK + nq * 4);
        float Bv[4] = { bl16(qb.x), bh16(qb.x), bl16(qb.y), bh16(qb.y) };
        const float du = delta * u;
#pragma unroll
        for (int i = 0; i < 4; i++) {
            float dA = __expf(delta * Ac[i]);
            h[i] = h[i] * dA + du * Bv[i];
            P[i] *= dA;
        }
    }
    size_t idx = ((size_t)c * DINNER + d) * DSTATE + nq * 4;
    float4v hv; hv[0] = h[0]; hv[1] = h[1]; hv[2] = h[2]; hv[3] = h[3];
    float4v pv; pv[0] = P[0]; pv[1] = P[1]; pv[2] = P[2]; pv[3] = P[3];
    *(float4v*)(hend + idx) = hv;
    *(float4v*)(Pbuf + idx) = pv;
}

// ---- combine: sequential over chunks; hend[c] is rewritten to H_in(c) ----
__global__ __launch_bounds__(256) void scan_combine(
    float* __restrict__ hend, const float* __restrict__ Pbuf)
{
    const int dn = blockIdx.x * 256 + threadIdx.x;   // (d,n) pair, 65536 total
    float H = 0.f;
    for (int c = 0; c < NCHUNK; ++c) {
        size_t idx = (size_t)c * (DINNER * DSTATE) + dn;
        float he = hend[idx];
        float p  = Pbuf[idx];
        hend[idx] = H;           // entry state for chunk c
        H = he + p * H;
    }
}

// ---- pass 3: rerun chunk scan seeded with H_in; emit gated y into z-slot ----
__global__ __launch_bounds__(256) void scan_chunk2(
    const float* __restrict__ dlt, const bf16* __restrict__ xc,
    bf16* __restrict__ xz, const bf16* __restrict__ xdbl,
    const float* __restrict__ A_log, const float* __restrict__ Dp,
    const float* __restrict__ Hin)
{
    const int nq = threadIdx.x & 3;
    const int d  = blockIdx.x * 64 + (threadIdx.x >> 2);
    const int c  = blockIdx.y;

    float Ac[4];
#pragma unroll
    for (int i = 0; i < 4; i++)
        Ac[i] = -__expf(A_log[d * DSTATE + nq * 4 + i]);
    const float Dv = Dp[d];

    float h[4];
    {
        float4v hv = *(const float4v*)(Hin + ((size_t)c * DINNER + d) * DSTATE + nq * 4);
        h[0] = hv[0]; h[1] = hv[1]; h[2] = hv[2]; h[3] = hv[3];
    }
    for (int l = c * LCHUNK; l < (c + 1) * LCHUNK; ++l) {
        const float delta = dlt[(size_t)l * DINNER + d];
        const float u     = b2f(xc[(size_t)l * DINNER + d]);
        const uint2 qb = *(const uint2*)(xdbl + (size_t)l * DXP + DTRANK + nq * 4);
        const uint2 qc = *(const uint2*)(xdbl + (size_t)l * DXP + DTRANK + DSTATE + nq * 4);
        float Bv[4] = { bl16(qb.x), bh16(qb.x), bl16(qb.y), bh16(qb.y) };
        float Cv[4] = { bl16(qc.x), bh16(qc.x), bl16(qc.y), bh16(qc.y) };
        const float du = delta * u;
        float yv = 0.f;
#pragma unroll
        for (int i = 0; i < 4; i++) {
            float dA = __expf(delta * Ac[i]);
            h[i] = h[i] * dA + du * Bv[i];
            yv += h[i] * Cv[i];
        }
        yv += __shfl_xor(yv, 1);
        yv += __shfl_xor(yv, 2);
        if (nq == 0) {
            yv += u * Dv;
            bf16* zp = xz + (size_t)l * (2 * DINNER) + DINNER + d;
            float z = b2f(*zp);
            yv *= z / (1.0f + __expf(-z));
            *zp = f2b(yv);
        }
    }
}

// ---- serial scan fallback (R4 shipping version) ----
template<typename DT>
__global__ __launch_bounds__(256) void scan_serial(
    const DT* __restrict__ dlt, bf16* __restrict__ xz,
    const bf16* __restrict__ xdbl,
    const float* __restrict__ A_log, const float* __restrict__ Dp)
{
    const int nq = threadIdx.x & 3;
    const int d  = blockIdx.x * 64 + (threadIdx.x >> 2);
    float Ac[4];
#pragma unroll
    for (int i = 0; i < 4; i++)
        Ac[i] = -__expf(A_log[d * DSTATE + nq * 4 + i]);
    const float Dv = Dp[d];
    float h[4] = {0.f, 0.f, 0.f, 0.f};
    for (int l = 0; l < LSEQ; ++l) {
        const float delta = cvtL<DT>(dlt[(size_t)l * DINNER + d]);
        const float u     = b2f(xz[(size_t)l * (2 * DINNER) + d]);
        const uint2 qb = *(const uint2*)(xdbl + (size_t)l * DXP + DTRANK + nq * 4);
        const uint2 qc = *(const uint2*)(xdbl + (size_t)l * DXP + DTRANK + DSTATE + nq * 4);
        float Bv[4] = { bl16(qb.x), bh16(qb.x), bl16(qb.y), bh16(qb.y) };
        float Cv[4] = { bl16(qc.x), bh16(qc.x), bl16(qc.y), bh16(qc.y) };
        const float du = delta * u;
        float yv = 0.f;
#pragma unroll
        for (int i = 0; i < 4; i++) {
            float dA = __expf(delta * Ac[i]);
            h[i] = h[i] * dA + du * Bv[i];
            yv += h[i] * Cv[i];
        }
        yv += __shfl_xor(yv, 1);
        yv += __shfl_xor(yv, 2);
        if (nq == 0) {
            yv += u * Dv;
            bf16* zp = xz + (size_t)l * (2 * DINNER) + DINNER + d;
            float z = b2f(*zp);
            yv *= z / (1.0f + __expf(-z));
            *zp = f2b(yv);
        }
    }
}

extern "C" void kernel_launch(void* const* d_in, const int* in_sizes, int n_in,
                              void* d_out, int out_size, void* d_ws, size_t ws_size,
                              hipStream_t stream)
{
    // Inputs are FLOAT32, setup_inputs() dict order.
    const float* hs      = (const float*)d_in[0];
    const float* w_in    = (const float*)d_in[1];
    const float* w_conv  = (const float*)d_in[2];
    const float* w_xproj = (const float*)d_in[3];
    const float* w_dt    = (const float*)d_in[4];
    const float *w_out, *b_dt, *A_log, *Dp;
    if (in_sizes[5] == DMODEL * DINNER) {
        w_out = (const float*)d_in[5];
        b_dt  = (const float*)d_in[6];
        A_log = (const float*)d_in[7];
        Dp    = (const float*)d_in[8];
    } else {
        b_dt  = (const float*)d_in[5];
        A_log = (const float*)d_in[6];
        Dp    = (const float*)d_in[7];
        w_out = (const float*)d_in[8];
    }
    float* out = (float*)d_out;

    const size_t SZ_XZ   = (size_t)LSEQ * 2 * DINNER * sizeof(bf16);   // 33.5 MB
    const size_t SZ_XC   = (size_t)LSEQ * DINNER * sizeof(bf16);       // 16.8 MB
    const size_t SZ_XDBL = (size_t)LSEQ * DXP * sizeof(bf16);          //  0.7 MB
    const size_t SZ_DLTF = (size_t)LSEQ * DINNER * sizeof(float);      // 33.5 MB
    const size_t SZ_HP   = (size_t)NCHUNK * DINNER * DSTATE * sizeof(float); // 16.8 MB

    char* p = (char*)d_ws;
    bf16* xz = (bf16*)p; p += SZ_XZ;

    const size_t need_fast = SZ_XZ + SZ_XC + SZ_XDBL + SZ_DLTF + 2 * SZ_HP; // ~118 MB
    const bool fast = ws_size >= need_fast;

    dim3 blk(256);

    // 1) xz[l][e] = sum_d hs[l][d] * w_in[e][d]
    gemm_bt<float, bf16, false><<<dim3(LSEQ / 64, (2 * DINNER) / 64), blk, 0, stream>>>(
        hs, DMODEL, w_in, DMODEL, xz, 2 * DINNER, LSEQ, 2 * DINNER, DMODEL, nullptr);

    if (fast) {
        bf16*  xc   = (bf16*)p;  p += SZ_XC;
        bf16*  xdbl = (bf16*)p;  p += SZ_XDBL;
        float* dlt  = (float*)p; p += SZ_DLTF;
        float* hend = (float*)p; p += SZ_HP;
        float* Pbuf = (float*)p;

        // 2) conv + silu, L-parallel, xz(x-half) -> xc
        conv_silu_par<<<dim3(DINNER / 256, LSEQ / 256), blk, 0, stream>>>(xz, w_conv, xc);

        // 3) x_proj from xc
        gemm_bt<bf16, bf16, false><<<dim3(LSEQ / 64, 3), blk, 0, stream>>>(
            xc, DINNER, w_xproj, DINNER, xdbl, DXP, LSEQ, DXP, DINNER, nullptr);

        // 4) dt_proj + softplus -> dlt (fp32)
        gemm_bt<bf16, float, true><<<dim3(LSEQ / 64, DINNER / 64), blk, 0, stream>>>(
            xdbl, DXP, w_dt, DTRANK, dlt, DINNER, LSEQ, DINNER, DTRANK, b_dt);

        // 5) chunk-parallel scan
        scan_chunk1<<<dim3(DINNER / 64, NCHUNK), blk, 0, stream>>>(
            dlt, xc, xdbl, A_log, hend, Pbuf);
        scan_combine<<<dim3(DINNER * DSTATE / 256), blk, 0, stream>>>(hend, Pbuf);
        scan_chunk2<<<dim3(DINNER / 64, NCHUNK), blk, 0, stream>>>(
            dlt, xc, xz, xdbl, A_log, Dp, hend);
    } else {
        // fallback tiers: in-place conv + serial scan (R4 layout)
        bf16* xdbl = (bf16*)p; p += SZ_XDBL;
        size_t used = (size_t)(p - (char*)d_ws);
        bool dlt_f32 = (ws_size - used) >= SZ_DLTF;

        conv_silu_inplace<<<dim3(DINNER / 256), blk, 0, stream>>>(xz, w_conv);
        gemm_bt<bf16, bf16, false><<<dim3(LSEQ / 64, 3), blk, 0, stream>>>(
            xz, 2 * DINNER, w_xproj, DINNER, xdbl, DXP, LSEQ, DXP, DINNER, nullptr);
        if (dlt_f32) {
            float* dlt = (float*)p;
            gemm_bt<bf16, float, true><<<dim3(LSEQ / 64, DINNER / 64), blk, 0, stream>>>(
                xdbl, DXP, w_dt, DTRANK, dlt, DINNER, LSEQ, DINNER, DTRANK, b_dt);
            scan_serial<float><<<dim3(DINNER / 64), blk, 0, stream>>>(dlt, xz, xdbl, A_log, Dp);
        } else {
            bf16* dlt = (bf16*)p;
            gemm_bt<bf16, bf16, true><<<dim3(LSEQ / 64, DINNER / 64), blk, 0, stream>>>(
                xdbl, DXP, w_dt, DTRANK, dlt, DINNER, LSEQ, DINNER, DTRANK, b_dt);
            scan_serial<bf16><<<dim3(DINNER / 64), blk, 0, stream>>>(dlt, xz, xdbl, A_log, Dp);
        }
    }

    // 6) out[l][m] = sum_d y[l][d] * w_out[m][d]   (A = z-half of xz, lda=8192)
    gemm_bt<bf16, float, false><<<dim3(LSEQ / 64, DMODEL / 64), blk, 0, stream>>>(
        xz + DINNER, 2 * DINNER, w_out, DINNER, out, DMODEL, LSEQ, DMODEL, DINNER, nullptr);
}

// Round 6
// 633.054 us; speedup vs baseline: 3.7583x; 1.1649x over previous
//
#include <hip/hip_runtime.h>
#include <hip/hip_bf16.h>

#define LSEQ 2048
#define DMODEL 2048
#define DINNER 4096
#define DSTATE 16
#define DTRANK 128
#define DCONV 4
#define DXP (DTRANK + 2*DSTATE)   // 160
#define NCHUNK 64
#define LCHUNK (LSEQ / NCHUNK)    // 32

using bf16 = __hip_bfloat16;
typedef __attribute__((ext_vector_type(8))) short short8;
typedef __attribute__((ext_vector_type(4))) float float4v;

__device__ __forceinline__ float b2f(bf16 v) { return __bfloat162float(v); }
__device__ __forceinline__ bf16 f2b(float v) { return __float2bfloat16(v); }
__device__ __forceinline__ float bl16(unsigned u) { return __uint_as_float(u << 16); }
__device__ __forceinline__ float bh16(unsigned u) { return __uint_as_float(u & 0xffff0000u); }

__device__ __forceinline__ short f2bs(float v) {
    bf16 b = __float2bfloat16(v);
    union { bf16 b; short s; } u; u.b = b; return u.s;
}

__device__ __forceinline__ short8 ld8(const float* p) {
    float4v f0 = *(const float4v*)p;
    float4v f1 = *(const float4v*)(p + 4);
    short8 r;
    r[0] = f2bs(f0[0]); r[1] = f2bs(f0[1]); r[2] = f2bs(f0[2]); r[3] = f2bs(f0[3]);
    r[4] = f2bs(f1[0]); r[5] = f2bs(f1[1]); r[6] = f2bs(f1[2]); r[7] = f2bs(f1[3]);
    return r;
}
__device__ __forceinline__ short8 ld8(const bf16* p) { return *(const short8*)p; }

template<typename CT> __device__ __forceinline__ CT cvtC(float v);
template<> __device__ __forceinline__ bf16  cvtC<bf16>(float v)  { return f2b(v); }
template<> __device__ __forceinline__ float cvtC<float>(float v) { return v; }

template<typename T> __device__ __forceinline__ float cvtL(T v);
template<> __device__ __forceinline__ float cvtL<bf16>(bf16 v)   { return b2f(v); }
template<> __device__ __forceinline__ float cvtL<float>(float v) { return v; }

// async global->LDS, 16 B per lane, dest = wave-uniform base + lane*16
__device__ __forceinline__ void glds16(const bf16* g, void* lds_base) {
    __builtin_amdgcn_global_load_lds(
        (const __attribute__((address_space(1))) void*)g,
        (__attribute__((address_space(3))) void*)lds_base, 16, 0, 0);
}

// ---- fp32 -> bf16 bulk convert (8 elem/thread, n % 2048 == 0) ----
__global__ __launch_bounds__(256) void cvt_f32_bf16(
    const float* __restrict__ src, bf16* __restrict__ dst, int n)
{
    int i = (blockIdx.x * 256 + threadIdx.x) * 8;
    if (i >= n) return;
    *(short8*)(dst + i) = ld8(src + i);
}

// ============================================================================
// m97-style GEMM: C[m][n] = sum_k A[m][k]*B[n][k], all-bf16 inputs,
// 128 x BN tile (BN=128 or 64), BK=32, global_load_lds dwordx4 staging,
// 4 waves, each 64 x BN/2 via 4 x (BN/32) mfma_f32_16x16x32_bf16.
// REQUIRES: M%128==0, N%BN==0, K%32==0 (no guards).
// ============================================================================
template<int BN, typename CT, bool SP>
__global__ __launch_bounds__(256) void gemm_bt_glds(
    const bf16* __restrict__ A, int lda,
    const bf16* __restrict__ B, int ldb,
    CT* __restrict__ C, int ldc,
    int K, const float* __restrict__ bias)
{
    constexpr int NJ = BN / 32;            // b-frags per wave (4 or 2)
    __shared__ bf16 As[128][32];           // 8 KB, rows of 64 B, NO padding (glds)
    __shared__ bf16 Bs[BN][32];

    const int t    = threadIdx.x;
    const int wave = t >> 6;
    const int lane = t & 63;
    const int t16  = lane & 15;
    const int quad = lane >> 4;
    const int wm   = (wave >> 1) * 64;
    const int wn   = (wave & 1) * (BN / 2);
    const int bm0  = blockIdx.x * 128;
    const int bn0  = blockIdx.y * BN;

    // staging lane map: row = +lane/4, k-seg = (lane%4)*8 elements
    const int lrow = lane >> 2;
    const int lseg = (lane & 3) * 8;

    const bf16* Ag0 = A + (size_t)(bm0 + wave * 32 + lrow) * lda + lseg;
    const bf16* Ag1 = Ag0 + (size_t)16 * lda;
    const bf16* Bg0;
    const bf16* Bg1 = nullptr;
    if (BN == 128) {
        Bg0 = B + (size_t)(bn0 + wave * 32 + lrow) * ldb + lseg;
        Bg1 = Bg0 + (size_t)16 * ldb;
    } else {
        Bg0 = B + (size_t)(bn0 + wave * 16 + lrow) * ldb + lseg;
    }
    char* As3 = (char*)&As[0][0];
    char* Bs3 = (char*)&Bs[0][0];
    char* Ad0 = As3 + (wave * 32) * 64;
    char* Ad1 = As3 + (wave * 32 + 16) * 64;
    char* Bd0 = (BN == 128) ? Bs3 + (wave * 32) * 64 : Bs3 + (wave * 16) * 64;
    char* Bd1 = Bs3 + (wave * 32 + 16) * 64;

    float4v acc[4][NJ];
#pragma unroll
    for (int i = 0; i < 4; i++)
#pragma unroll
        for (int j = 0; j < NJ; j++) acc[i][j] = (float4v)(0.0f);

    for (int k0 = 0; k0 < K; k0 += 32) {
        __syncthreads();                   // previous tile's readers done
        glds16(Ag0 + k0, Ad0);
        glds16(Ag1 + k0, Ad1);
        glds16(Bg0 + k0, Bd0);
        if (BN == 128) glds16(Bg1 + k0, Bd1);
        __syncthreads();                   // vmcnt drained before barrier -> data visible

        short8 a[4], b[NJ];
#pragma unroll
        for (int mi = 0; mi < 4; mi++)
            a[mi] = *(const short8*)(&As[wm + mi * 16 + t16][quad * 8]);
#pragma unroll
        for (int nj = 0; nj < NJ; nj++)
            b[nj] = *(const short8*)(&Bs[wn + nj * 16 + t16][quad * 8]);
#pragma unroll
        for (int mi = 0; mi < 4; mi++)
#pragma unroll
            for (int nj = 0; nj < NJ; nj++)
                acc[mi][nj] = __builtin_amdgcn_mfma_f32_16x16x32_bf16(
                    a[mi], b[nj], acc[mi][nj], 0, 0, 0);
    }

#pragma unroll
    for (int mi = 0; mi < 4; mi++) {
#pragma unroll
        for (int nj = 0; nj < NJ; nj++) {
            int n_g = bn0 + wn + nj * 16 + t16;
            float bia = SP ? bias[n_g] : 0.0f;
#pragma unroll
            for (int r = 0; r < 4; r++) {
                int m_g = bm0 + wm + mi * 16 + quad * 4 + r;
                float v = acc[mi][nj][r];
                if (SP) {
                    float x = v + bia;
                    v = (x > 20.0f) ? x : log1pf(__expf(x));
                }
                C[(size_t)m_g * ldc + n_g] = cvtC<CT>(v);
            }
        }
    }
}

// ---- old guarded 64x64 GEMM (x_proj N=160 + fallback tiers); B is fp32 ----
template<typename AT, typename CT, bool SP>
__global__ __launch_bounds__(256) void gemm_bt(
    const AT* __restrict__ A, int lda,
    const float* __restrict__ B, int ldb,
    CT* __restrict__ C, int ldc,
    int M, int N, int K,
    const float* __restrict__ bias)
{
    __shared__ bf16 As[64][40];
    __shared__ bf16 Bs[64][40];

    const int t    = threadIdx.x;
    const int bm0  = blockIdx.x * 64;
    const int bn0  = blockIdx.y * 64;
    const int row  = t >> 2;
    const int seg  = (t & 3) * 8;
    const int wave = t >> 6;
    const int lane = t & 63;
    const int wm   = (wave >> 1) * 32;
    const int wn   = (wave & 1) * 32;
    const int t16  = lane & 15;
    const int quad = lane >> 4;

    float4v acc[2][2];
#pragma unroll
    for (int i = 0; i < 2; i++)
#pragma unroll
        for (int j = 0; j < 2; j++) acc[i][j] = (float4v)(0.0f);

    const AT*    Aptr = A + (size_t)(bm0 + row) * lda + seg;
    const float* Bptr = B + (size_t)(bn0 + row) * ldb + seg;
    const bool a_ok = (bm0 + row) < M;
    const bool b_ok = (bn0 + row) < N;
    const short8 zero8 = (short8)(0);

    for (int k0 = 0; k0 < K; k0 += 32) {
        short8 av = a_ok ? ld8(Aptr + k0) : zero8;
        short8 bv = b_ok ? ld8(Bptr + k0) : zero8;
        __syncthreads();
        *(short8*)(&As[row][seg]) = av;
        *(short8*)(&Bs[row][seg]) = bv;
        __syncthreads();

        short8 a0 = *(const short8*)(&As[wm + t16][quad * 8]);
        short8 a1 = *(const short8*)(&As[wm + 16 + t16][quad * 8]);
        short8 b0 = *(const short8*)(&Bs[wn + t16][quad * 8]);
        short8 b1 = *(const short8*)(&Bs[wn + 16 + t16][quad * 8]);
        acc[0][0] = __builtin_amdgcn_mfma_f32_16x16x32_bf16(a0, b0, acc[0][0], 0, 0, 0);
        acc[0][1] = __builtin_amdgcn_mfma_f32_16x16x32_bf16(a0, b1, acc[0][1], 0, 0, 0);
        acc[1][0] = __builtin_amdgcn_mfma_f32_16x16x32_bf16(a1, b0, acc[1][0], 0, 0, 0);
        acc[1][1] = __builtin_amdgcn_mfma_f32_16x16x32_bf16(a1, b1, acc[1][1], 0, 0, 0);
    }

#pragma unroll
    for (int i = 0; i < 2; i++) {
#pragma unroll
        for (int j = 0; j < 2; j++) {
            int n_g = bn0 + wn + j * 16 + t16;
            if (n_g >= N) continue;
            float bia = SP ? bias[n_g] : 0.0f;
#pragma unroll
            for (int r = 0; r < 4; r++) {
                int m_g = bm0 + wm + i * 16 + quad * 4 + r;
                if (m_g >= M) continue;
                float v = acc[i][j][r];
                if (SP) {
                    float x = v + bia;
                    v = (x > 20.0f) ? x : log1pf(__expf(x));
                }
                C[(size_t)m_g * ldc + n_g] = cvtC<CT>(v);
            }
        }
    }
}

// ---- conv, L-parallel: reads xz (x-half), writes xc ----
__global__ __launch_bounds__(256) void conv_silu_par(
    const bf16* __restrict__ xz, const float* __restrict__ w, bf16* __restrict__ xc)
{
    const int d  = blockIdx.x * 256 + threadIdx.x;
    const int lc = blockIdx.y * 256;
    const float w0 = w[d * 4 + 0];
    const float w1 = w[d * 4 + 1];
    const float w2 = w[d * 4 + 2];
    const float w3 = w[d * 4 + 3];
    const size_t S = 2 * DINNER;
    const bf16* p = xz + d;
    float xm3 = 0.f, xm2 = 0.f, xm1 = 0.f;
    if (lc >= 3) {
        xm3 = b2f(p[(size_t)(lc - 3) * S]);
        xm2 = b2f(p[(size_t)(lc - 2) * S]);
        xm1 = b2f(p[(size_t)(lc - 1) * S]);
    }
    for (int l = lc; l < lc + 256; ++l) {
        float x0 = b2f(p[(size_t)l * S]);
        float a = w0 * xm3 + w1 * xm2 + w2 * xm1 + w3 * x0;
        xc[(size_t)l * DINNER + d] = f2b(a / (1.0f + __expf(-a)));
        xm3 = xm2; xm2 = xm1; xm1 = x0;
    }
}

// ---- conv, serial in-place fallback ----
__global__ __launch_bounds__(256) void conv_silu_inplace(
    bf16* __restrict__ xz, const float* __restrict__ w)
{
    const int d = blockIdx.x * 256 + threadIdx.x;
    const float w0 = w[d * 4 + 0];
    const float w1 = w[d * 4 + 1];
    const float w2 = w[d * 4 + 2];
    const float w3 = w[d * 4 + 3];
    bf16* p = xz + d;
    const size_t S = 2 * DINNER;
    float xm3 = 0.f, xm2 = 0.f, xm1 = 0.f;
    for (int l = 0; l < LSEQ; l += 4) {
        float x0 = b2f(p[(size_t)(l + 0) * S]);
        float x1 = b2f(p[(size_t)(l + 1) * S]);
        float x2 = b2f(p[(size_t)(l + 2) * S]);
        float x3 = b2f(p[(size_t)(l + 3) * S]);
        float a0 = w0 * xm3 + w1 * xm2 + w2 * xm1 + w3 * x0;
        float a1 = w0 * xm2 + w1 * xm1 + w2 * x0  + w3 * x1;
        float a2 = w0 * xm1 + w1 * x0  + w2 * x1  + w3 * x2;
        float a3 = w0 * x0  + w1 * x1  + w2 * x2  + w3 * x3;
        p[(size_t)(l + 0) * S] = f2b(a0 / (1.0f + __expf(-a0)));
        p[(size_t)(l + 1) * S] = f2b(a1 / (1.0f + __expf(-a1)));
        p[(size_t)(l + 2) * S] = f2b(a2 / (1.0f + __expf(-a2)));
        p[(size_t)(l + 3) * S] = f2b(a3 / (1.0f + __expf(-a3)));
        xm3 = x1; xm2 = x2; xm1 = x3;
    }
}

// ---- chunked scan pass 1 ----
__global__ __launch_bounds__(256) void scan_chunk1(
    const float* __restrict__ dlt, const bf16* __restrict__ xc,
    const bf16* __restrict__ xdbl, const float* __restrict__ A_log,
    float* __restrict__ hend, float* __restrict__ Pbuf)
{
    const int nq = threadIdx.x & 3;
    const int d  = blockIdx.x * 64 + (threadIdx.x >> 2);
    const int c  = blockIdx.y;

    float Ac[4];
#pragma unroll
    for (int i = 0; i < 4; i++)
        Ac[i] = -__expf(A_log[d * DSTATE + nq * 4 + i]);

    float h[4] = {0.f, 0.f, 0.f, 0.f};
    float P[4] = {1.f, 1.f, 1.f, 1.f};
    for (int l = c * LCHUNK; l < (c + 1) * LCHUNK; ++l) {
        const float delta = dlt[(size_t)l * DINNER + d];
        const float u     = b2f(xc[(size_t)l * DINNER + d]);
        const uint2 qb = *(const uint2*)(xdbl + (size_t)l * DXP + DTRANK + nq * 4);
        float Bv[4] = { bl16(qb.x), bh16(qb.x), bl16(qb.y), bh16(qb.y) };
        const float du = delta * u;
#pragma unroll
        for (int i = 0; i < 4; i++) {
            float dA = __expf(delta * Ac[i]);
            h[i] = h[i] * dA + du * Bv[i];
            P[i] *= dA;
        }
    }
    size_t idx = ((size_t)c * DINNER + d) * DSTATE + nq * 4;
    float4v hv; hv[0] = h[0]; hv[1] = h[1]; hv[2] = h[2]; hv[3] = h[3];
    float4v pv; pv[0] = P[0]; pv[1] = P[1]; pv[2] = P[2]; pv[3] = P[3];
    *(float4v*)(hend + idx) = hv;
    *(float4v*)(Pbuf + idx) = pv;
}

// ---- combine ----
__global__ __launch_bounds__(256) void scan_combine(
    float* __restrict__ hend, const float* __restrict__ Pbuf)
{
    const int dn = blockIdx.x * 256 + threadIdx.x;
    float H = 0.f;
    for (int c = 0; c < NCHUNK; ++c) {
        size_t idx = (size_t)c * (DINNER * DSTATE) + dn;
        float he = hend[idx];
        float p  = Pbuf[idx];
        hend[idx] = H;
        H = he + p * H;
    }
}

// ---- pass 3 ----
__global__ __launch_bounds__(256) void scan_chunk2(
    const float* __restrict__ dlt, const bf16* __restrict__ xc,
    bf16* __restrict__ xz, const bf16* __restrict__ xdbl,
    const float* __restrict__ A_log, const float* __restrict__ Dp,
    const float* __restrict__ Hin)
{
    const int nq = threadIdx.x & 3;
    const int d  = blockIdx.x * 64 + (threadIdx.x >> 2);
    const int c  = blockIdx.y;

    float Ac[4];
#pragma unroll
    for (int i = 0; i < 4; i++)
        Ac[i] = -__expf(A_log[d * DSTATE + nq * 4 + i]);
    const float Dv = Dp[d];

    float h[4];
    {
        float4v hv = *(const float4v*)(Hin + ((size_t)c * DINNER + d) * DSTATE + nq * 4);
        h[0] = hv[0]; h[1] = hv[1]; h[2] = hv[2]; h[3] = hv[3];
    }
    for (int l = c * LCHUNK; l < (c + 1) * LCHUNK; ++l) {
        const float delta = dlt[(size_t)l * DINNER + d];
        const float u     = b2f(xc[(size_t)l * DINNER + d]);
        const uint2 qb = *(const uint2*)(xdbl + (size_t)l * DXP + DTRANK + nq * 4);
        const uint2 qc = *(const uint2*)(xdbl + (size_t)l * DXP + DTRANK + DSTATE + nq * 4);
        float Bv[4] = { bl16(qb.x), bh16(qb.x), bl16(qb.y), bh16(qb.y) };
        float Cv[4] = { bl16(qc.x), bh16(qc.x), bl16(qc.y), bh16(qc.y) };
        const float du = delta * u;
        float yv = 0.f;
#pragma unroll
        for (int i = 0; i < 4; i++) {
            float dA = __expf(delta * Ac[i]);
            h[i] = h[i] * dA + du * Bv[i];
            yv += h[i] * Cv[i];
        }
        yv += __shfl_xor(yv, 1);
        yv += __shfl_xor(yv, 2);
        if (nq == 0) {
            yv += u * Dv;
            bf16* zp = xz + (size_t)l * (2 * DINNER) + DINNER + d;
            float z = b2f(*zp);
            yv *= z / (1.0f + __expf(-z));
            *zp = f2b(yv);
        }
    }
}

// ---- serial scan fallback ----
template<typename DT>
__global__ __launch_bounds__(256) void scan_serial(
    const DT* __restrict__ dlt, bf16* __restrict__ xz,
    const bf16* __restrict__ xdbl,
    const float* __restrict__ A_log, const float* __restrict__ Dp)
{
    const int nq = threadIdx.x & 3;
    const int d  = blockIdx.x * 64 + (threadIdx.x >> 2);
    float Ac[4];
#pragma unroll
    for (int i = 0; i < 4; i++)
        Ac[i] = -__expf(A_log[d * DSTATE + nq * 4 + i]);
    const float Dv = Dp[d];
    float h[4] = {0.f, 0.f, 0.f, 0.f};
    for (int l = 0; l < LSEQ; ++l) {
        const float delta = cvtL<DT>(dlt[(size_t)l * DINNER + d]);
        const float u     = b2f(xz[(size_t)l * (2 * DINNER) + d]);
        const uint2 qb = *(const uint2*)(xdbl + (size_t)l * DXP + DTRANK + nq * 4);
        const uint2 qc = *(const uint2*)(xdbl + (size_t)l * DXP + DTRANK + DSTATE + nq * 4);
        float Bv[4] = { bl16(qb.x), bh16(qb.x), bl16(qb.y), bh16(qb.y) };
        float Cv[4] = { bl16(qc.x), bh16(qc.x), bl16(qc.y), bh16(qc.y) };
        const float du = delta * u;
        float yv = 0.f;
#pragma unroll
        for (int i = 0; i < 4; i++) {
            float dA = __expf(delta * Ac[i]);
            h[i] = h[i] * dA + du * Bv[i];
            yv += h[i] * Cv[i];
        }
        yv += __shfl_xor(yv, 1);
        yv += __shfl_xor(yv, 2);
        if (nq == 0) {
            yv += u * Dv;
            bf16* zp = xz + (size_t)l * (2 * DINNER) + DINNER + d;
            float z = b2f(*zp);
            yv *= z / (1.0f + __expf(-z));
            *zp = f2b(yv);
        }
    }
}

extern "C" void kernel_launch(void* const* d_in, const int* in_sizes, int n_in,
                              void* d_out, int out_size, void* d_ws, size_t ws_size,
                              hipStream_t stream)
{
    // Inputs FLOAT32, setup_inputs() dict order.
    const float* hs      = (const float*)d_in[0];
    const float* w_in    = (const float*)d_in[1];
    const float* w_conv  = (const float*)d_in[2];
    const float* w_xproj = (const float*)d_in[3];
    const float* w_dt    = (const float*)d_in[4];
    const float *w_out, *b_dt, *A_log, *Dp;
    if (in_sizes[5] == DMODEL * DINNER) {
        w_out = (const float*)d_in[5];
        b_dt  = (const float*)d_in[6];
        A_log = (const float*)d_in[7];
        Dp    = (const float*)d_in[8];
    } else {
        b_dt  = (const float*)d_in[5];
        A_log = (const float*)d_in[6];
        Dp    = (const float*)d_in[7];
        w_out = (const float*)d_in[8];
    }
    float* out = (float*)d_out;

    const size_t SZ_XZ   = (size_t)LSEQ * 2 * DINNER * sizeof(bf16);         // 33.5 MB
    const size_t SZ_XC   = (size_t)LSEQ * DINNER * sizeof(bf16);             // 16.8 MB
    const size_t SZ_XDBL = (size_t)LSEQ * DXP * sizeof(bf16);                //  0.7 MB
    const size_t SZ_DLTF = (size_t)LSEQ * DINNER * sizeof(float);            // 33.5 MB
    const size_t SZ_HP   = (size_t)NCHUNK * DINNER * DSTATE * sizeof(float); // 16.8 MB

    char* p = (char*)d_ws;
    bf16* xz = (bf16*)p; p += SZ_XZ;

    const size_t need_fast = SZ_XZ + SZ_XC + SZ_XDBL + SZ_DLTF + 2 * SZ_HP; // 118 MB
    const bool fast = ws_size >= need_fast;

    dim3 blk(256);

    if (fast) {
        bf16*  xc   = (bf16*)p;  p += SZ_XC;
        bf16*  xdbl = (bf16*)p;  p += SZ_XDBL;
        char*  dreg = p;         p += SZ_DLTF;   // dlt fp32; hs_bf16 before stage 4
        char*  hpr  = p;                          // hend+Pbuf; w_in_bf16 / w_dt_bf16 earlier
        float* dlt  = (float*)dreg;
        float* hend = (float*)hpr;
        float* Pbuf = (float*)(hpr + SZ_HP);

        // time-aliased bf16 copies (sequential stream makes this safe):
        bf16* hs_b   = (bf16*)dreg;   // dead once in_proj done (dlt written stage 4)
        bf16* w_in_b = (bf16*)hpr;    // dead once in_proj done (hend/Pbuf written stage 5)
        bf16* w_dt_b = (bf16*)hpr;    // written after in_proj, dead before scan
        bf16* w_out_b= (bf16*)xc;     // written after scan_chunk2, xc dead by then

        // 0) converts needed for in_proj
        cvt_f32_bf16<<<dim3((2*DINNER*DMODEL)/2048), blk, 0, stream>>>(w_in, w_in_b, 2*DINNER*DMODEL);
        cvt_f32_bf16<<<dim3((LSEQ*DMODEL)/2048), blk, 0, stream>>>(hs, hs_b, LSEQ*DMODEL);

        // 1) in_proj: xz[l][e] = sum_d hs[l][d] * w_in[e][d]
        gemm_bt_glds<128, bf16, false><<<dim3(LSEQ/128, (2*DINNER)/128), blk, 0, stream>>>(
            hs_b, DMODEL, w_in_b, DMODEL, xz, 2*DINNER, DMODEL, nullptr);

        // 2) conv + silu -> xc
        conv_silu_par<<<dim3(DINNER/256, LSEQ/256), blk, 0, stream>>>(xz, w_conv, xc);

        // 3) x_proj (N=160, guarded 64-tile)
        gemm_bt<bf16, bf16, false><<<dim3(LSEQ/64, 3), blk, 0, stream>>>(
            xc, DINNER, w_xproj, DINNER, xdbl, DXP, LSEQ, DXP, DINNER, nullptr);

        // 4) dt_proj + softplus -> dlt fp32 (overwrites hs_b region)
        cvt_f32_bf16<<<dim3((DINNER*DTRANK)/2048), blk, 0, stream>>>(w_dt, w_dt_b, DINNER*DTRANK);
        gemm_bt_glds<128, float, true><<<dim3(LSEQ/128, DINNER/128), blk, 0, stream>>>(
            xdbl, DXP, w_dt_b, DTRANK, dlt, DINNER, DTRANK, b_dt);

        // 5) chunk-parallel scan (hend/Pbuf overwrite w_in_b/w_dt_b region)
        scan_chunk1<<<dim3(DINNER/64, NCHUNK), blk, 0, stream>>>(
            dlt, xc, xdbl, A_log, hend, Pbuf);
        scan_combine<<<dim3(DINNER*DSTATE/256), blk, 0, stream>>>(hend, Pbuf);
        scan_chunk2<<<dim3(DINNER/64, NCHUNK), blk, 0, stream>>>(
            dlt, xc, xz, xdbl, A_log, Dp, hend);

        // 6) out_proj (BN=64 -> 512 blocks; xc dead, reuse for w_out_b)
        cvt_f32_bf16<<<dim3((DMODEL*DINNER)/2048), blk, 0, stream>>>(w_out, w_out_b, DMODEL*DINNER);
        gemm_bt_glds<64, float, false><<<dim3(LSEQ/128, DMODEL/64), blk, 0, stream>>>(
            xz + DINNER, 2*DINNER, w_out_b, DINNER, out, DMODEL, DINNER, nullptr);
    } else {
        // fallback tiers: R4 layout (in-place conv + serial scan, fp32-B gemms)
        bf16* xdbl = (bf16*)p; p += SZ_XDBL;
        size_t used = (size_t)(p - (char*)d_ws);
        bool dlt_f32 = (ws_size - used) >= SZ_DLTF;

        gemm_bt<float, bf16, false><<<dim3(LSEQ/64, (2*DINNER)/64), blk, 0, stream>>>(
            hs, DMODEL, w_in, DMODEL, xz, 2*DINNER, LSEQ, 2*DINNER, DMODEL, nullptr);
        conv_silu_inplace<<<dim3(DINNER/256), blk, 0, stream>>>(xz, w_conv);
        gemm_bt<bf16, bf16, false><<<dim3(LSEQ/64, 3), blk, 0, stream>>>(
            xz, 2*DINNER, w_xproj, DINNER, xdbl, DXP, LSEQ, DXP, DINNER, nullptr);
        if (dlt_f32) {
            float* dlt = (float*)p;
            gemm_bt<bf16, float, true><<<dim3(LSEQ/64, DINNER/64), blk, 0, stream>>>(
                xdbl, DXP, w_dt, DTRANK, dlt, DINNER, LSEQ, DINNER, DTRANK, b_dt);
            scan_serial<float><<<dim3(DINNER/64), blk, 0, stream>>>(dlt, xz, xdbl, A_log, Dp);
        } else {
            bf16* dlt = (bf16*)p;
            gemm_bt<bf16, bf16, true><<<dim3(LSEQ/64, DINNER/64), blk, 0, stream>>>(
                xdbl, DXP, w_dt, DTRANK, dlt, DINNER, LSEQ, DINNER, DTRANK, b_dt);
            scan_serial<bf16><<<dim3(DINNER/64), blk, 0, stream>>>(dlt, xz, xdbl, A_log, Dp);
        }
        gemm_bt<bf16, float, false><<<dim3(LSEQ/64, DMODEL/64), blk, 0, stream>>>(
            xz + DINNER, 2*DINNER, w_out, DINNER, out, DMODEL, LSEQ, DMODEL, DINNER, nullptr);
    }
}

// Round 7
// 601.095 us; speedup vs baseline: 3.9581x; 1.0532x over previous
//
#include <hip/hip_runtime.h>
#include <hip/hip_bf16.h>

#define LSEQ 2048
#define DMODEL 2048
#define DINNER 4096
#define DSTATE 16
#define DTRANK 128
#define DCONV 4
#define DXP (DTRANK + 2*DSTATE)   // 160
#define NCHUNK 64
#define LCHUNK (LSEQ / NCHUNK)    // 32

using bf16 = __hip_bfloat16;
typedef __attribute__((ext_vector_type(8))) short short8;
typedef __attribute__((ext_vector_type(4))) float float4v;

__device__ __forceinline__ float b2f(bf16 v) { return __bfloat162float(v); }
__device__ __forceinline__ bf16 f2b(float v) { return __float2bfloat16(v); }
__device__ __forceinline__ float bl16(unsigned u) { return __uint_as_float(u << 16); }
__device__ __forceinline__ float bh16(unsigned u) { return __uint_as_float(u & 0xffff0000u); }

__device__ __forceinline__ short f2bs(float v) {
    bf16 b = __float2bfloat16(v);
    union { bf16 b; short s; } u; u.b = b; return u.s;
}

__device__ __forceinline__ short8 ld8(const float* p) {
    float4v f0 = *(const float4v*)p;
    float4v f1 = *(const float4v*)(p + 4);
    short8 r;
    r[0] = f2bs(f0[0]); r[1] = f2bs(f0[1]); r[2] = f2bs(f0[2]); r[3] = f2bs(f0[3]);
    r[4] = f2bs(f1[0]); r[5] = f2bs(f1[1]); r[6] = f2bs(f1[2]); r[7] = f2bs(f1[3]);
    return r;
}
__device__ __forceinline__ short8 ld8(const bf16* p) { return *(const short8*)p; }

template<typename CT> __device__ __forceinline__ CT cvtC(float v);
template<> __device__ __forceinline__ bf16  cvtC<bf16>(float v)  { return f2b(v); }
template<> __device__ __forceinline__ float cvtC<float>(float v) { return v; }

template<typename T> __device__ __forceinline__ float cvtL(T v);
template<> __device__ __forceinline__ float cvtL<bf16>(bf16 v)   { return b2f(v); }
template<> __device__ __forceinline__ float cvtL<float>(float v) { return v; }

// async global->LDS, 16 B per lane, dest = wave-uniform base + lane*16
__device__ __forceinline__ void glds16(const bf16* g, void* lds_base) {
    __builtin_amdgcn_global_load_lds(
        (const __attribute__((address_space(1))) void*)g,
        (__attribute__((address_space(3))) void*)lds_base, 16, 0, 0);
}

// ---- fused fp32->bf16 convert of three arrays (each n % 2048 == 0) ----
__global__ __launch_bounds__(256) void cvt3(
    const float* __restrict__ s0, bf16* __restrict__ d0, int n0,
    const float* __restrict__ s1, bf16* __restrict__ d1, int n1,
    const float* __restrict__ s2, bf16* __restrict__ d2, int n2)
{
    const int b = blockIdx.x;
    const int nb0 = n0 >> 11, nb1 = n1 >> 11;
    const float* s; bf16* d; int i;
    if (b < nb0)            { s = s0; d = d0; i = b * 2048; }
    else if (b < nb0 + nb1) { s = s1; d = d1; i = (b - nb0) * 2048; }
    else                    { s = s2; d = d2; i = (b - nb0 - nb1) * 2048; }
    i += threadIdx.x * 8;
    *(short8*)(d + i) = ld8(s + i);
}

__global__ __launch_bounds__(256) void cvt1(
    const float* __restrict__ src, bf16* __restrict__ dst, int n)
{
    int i = (blockIdx.x * 256 + threadIdx.x) * 8;
    if (i >= n) return;
    *(short8*)(dst + i) = ld8(src + i);
}

// ============================================================================
// BK=64 glds GEMM: C[m][n] = sum_k A[m][k]*B[n][k], all-bf16 inputs.
// 128 x BN tile, BK=64, XOR-16B LDS swizzle (rows are 128 B -> without swizzle
// all 16 t16-rows alias one bank group; with s^(row&7) each b128 read spreads
// exactly 8 lanes/bank = conflict-free). 4 waves, 32 MFMA/wave per K-iter.
// REQUIRES: M%128==0, N%BN==0, K%64==0.
// ============================================================================
template<int BN, typename CT, bool SP>
__global__ __launch_bounds__(256) void gemm_glds64(
    const bf16* __restrict__ A, int lda,
    const bf16* __restrict__ B, int ldb,
    CT* __restrict__ C, int ldc,
    int K, const float* __restrict__ bias)
{
    constexpr int NJ  = BN / 32;          // b-frags per wave (4 or 2)
    constexpr int BGL = BN / 32;          // B glds per wave  (4 or 2)
    __shared__ bf16 As[128][64];          // 16 KB
    __shared__ bf16 Bs[BN][64];           // 16 or 8 KB

    const int t    = threadIdx.x;
    const int wave = t >> 6;
    const int lane = t & 63;
    const int t16  = lane & 15;
    const int quad = lane >> 4;
    const int wm   = (wave >> 1) * 64;
    const int wn   = (wave & 1) * (BN / 2);
    const int bm0  = blockIdx.x * 128;
    const int bn0  = blockIdx.y * BN;

    // staging: one glds = 64 lanes x 16B = 8 rows x 128B. lane -> (lrow, seg),
    // global seg XOR-swizzled so LDS slot s holds global group s^(row&7).
    const int lrow = lane >> 3;
    const int gseg = (((lane & 7) ^ lrow) * 8);

    const bf16* Ag[4]; char* Ad[4];
#pragma unroll
    for (int g = 0; g < 4; g++) {
        Ag[g] = A + (size_t)(bm0 + wave * 32 + g * 8 + lrow) * lda + gseg;
        Ad[g] = (char*)As + (wave * 32 + g * 8) * 128;
    }
    const bf16* Bg[BGL]; char* Bd[BGL];
#pragma unroll
    for (int g = 0; g < BGL; g++) {
        int r = (BN == 128) ? (wave * 32 + g * 8) : (wave * 16 + g * 8);
        Bg[g] = B + (size_t)(bn0 + r + lrow) * ldb + gseg;
        Bd[g] = (char*)Bs + r * 128;
    }

    float4v acc[4][NJ];
#pragma unroll
    for (int i = 0; i < 4; i++)
#pragma unroll
        for (int j = 0; j < NJ; j++) acc[i][j] = (float4v)(0.0f);

    const int sw = t16 & 7;               // row&7 for all fragment rows

    for (int k0 = 0; k0 < K; k0 += 64) {
        __syncthreads();
#pragma unroll
        for (int g = 0; g < 4; g++)   glds16(Ag[g] + k0, Ad[g]);
#pragma unroll
        for (int g = 0; g < BGL; g++) glds16(Bg[g] + k0, Bd[g]);
        __syncthreads();

#pragma unroll
        for (int kk = 0; kk < 2; kk++) {
            const int kso = ((kk * 4 + quad) ^ sw) * 8;
            short8 a[4], b[NJ];
#pragma unroll
            for (int mi = 0; mi < 4; mi++)
                a[mi] = *(const short8*)(&As[wm + mi * 16 + t16][kso]);
#pragma unroll
            for (int nj = 0; nj < NJ; nj++)
                b[nj] = *(const short8*)(&Bs[wn + nj * 16 + t16][kso]);
#pragma unroll
            for (int mi = 0; mi < 4; mi++)
#pragma unroll
                for (int nj = 0; nj < NJ; nj++)
                    acc[mi][nj] = __builtin_amdgcn_mfma_f32_16x16x32_bf16(
                        a[mi], b[nj], acc[mi][nj], 0, 0, 0);
        }
    }

#pragma unroll
    for (int mi = 0; mi < 4; mi++) {
#pragma unroll
        for (int nj = 0; nj < NJ; nj++) {
            int n_g = bn0 + wn + nj * 16 + t16;
            float bia = SP ? bias[n_g] : 0.0f;
#pragma unroll
            for (int r = 0; r < 4; r++) {
                int m_g = bm0 + wm + mi * 16 + quad * 4 + r;
                float v = acc[mi][nj][r];
                if (SP) {
                    float x = v + bia;
                    v = (x > 20.0f) ? x : log1pf(__expf(x));
                }
                C[(size_t)m_g * ldc + n_g] = cvtC<CT>(v);
            }
        }
    }
}

// ---- guarded 64x64 GEMM (x_proj N=160 + fallback tiers); B is fp32 ----
template<typename AT, typename CT, bool SP>
__global__ __launch_bounds__(256) void gemm_bt(
    const AT* __restrict__ A, int lda,
    const float* __restrict__ B, int ldb,
    CT* __restrict__ C, int ldc,
    int M, int N, int K,
    const float* __restrict__ bias)
{
    __shared__ bf16 As[64][40];
    __shared__ bf16 Bs[64][40];

    const int t    = threadIdx.x;
    const int bm0  = blockIdx.x * 64;
    const int bn0  = blockIdx.y * 64;
    const int row  = t >> 2;
    const int seg  = (t & 3) * 8;
    const int wave = t >> 6;
    const int lane = t & 63;
    const int wm   = (wave >> 1) * 32;
    const int wn   = (wave & 1) * 32;
    const int t16  = lane & 15;
    const int quad = lane >> 4;

    float4v acc[2][2];
#pragma unroll
    for (int i = 0; i < 2; i++)
#pragma unroll
        for (int j = 0; j < 2; j++) acc[i][j] = (float4v)(0.0f);

    const AT*    Aptr = A + (size_t)(bm0 + row) * lda + seg;
    const float* Bptr = B + (size_t)(bn0 + row) * ldb + seg;
    const bool a_ok = (bm0 + row) < M;
    const bool b_ok = (bn0 + row) < N;
    const short8 zero8 = (short8)(0);

    for (int k0 = 0; k0 < K; k0 += 32) {
        short8 av = a_ok ? ld8(Aptr + k0) : zero8;
        short8 bv = b_ok ? ld8(Bptr + k0) : zero8;
        __syncthreads();
        *(short8*)(&As[row][seg]) = av;
        *(short8*)(&Bs[row][seg]) = bv;
        __syncthreads();

        short8 a0 = *(const short8*)(&As[wm + t16][quad * 8]);
        short8 a1 = *(const short8*)(&As[wm + 16 + t16][quad * 8]);
        short8 b0 = *(const short8*)(&Bs[wn + t16][quad * 8]);
        short8 b1 = *(const short8*)(&Bs[wn + 16 + t16][quad * 8]);
        acc[0][0] = __builtin_amdgcn_mfma_f32_16x16x32_bf16(a0, b0, acc[0][0], 0, 0, 0);
        acc[0][1] = __builtin_amdgcn_mfma_f32_16x16x32_bf16(a0, b1, acc[0][1], 0, 0, 0);
        acc[1][0] = __builtin_amdgcn_mfma_f32_16x16x32_bf16(a1, b0, acc[1][0], 0, 0, 0);
        acc[1][1] = __builtin_amdgcn_mfma_f32_16x16x32_bf16(a1, b1, acc[1][1], 0, 0, 0);
    }

#pragma unroll
    for (int i = 0; i < 2; i++) {
#pragma unroll
        for (int j = 0; j < 2; j++) {
            int n_g = bn0 + wn + j * 16 + t16;
            if (n_g >= N) continue;
            float bia = SP ? bias[n_g] : 0.0f;
#pragma unroll
            for (int r = 0; r < 4; r++) {
                int m_g = bm0 + wm + i * 16 + quad * 4 + r;
                if (m_g >= M) continue;
                float v = acc[i][j][r];
                if (SP) {
                    float x = v + bia;
                    v = (x > 20.0f) ? x : log1pf(__expf(x));
                }
                C[(size_t)m_g * ldc + n_g] = cvtC<CT>(v);
            }
        }
    }
}

// ---- conv, L-parallel: reads xz (x-half), writes xc ----
__global__ __launch_bounds__(256) void conv_silu_par(
    const bf16* __restrict__ xz, const float* __restrict__ w, bf16* __restrict__ xc)
{
    const int d  = blockIdx.x * 256 + threadIdx.x;
    const int lc = blockIdx.y * 256;
    const float w0 = w[d * 4 + 0];
    const float w1 = w[d * 4 + 1];
    const float w2 = w[d * 4 + 2];
    const float w3 = w[d * 4 + 3];
    const size_t S = 2 * DINNER;
    const bf16* p = xz + d;
    float xm3 = 0.f, xm2 = 0.f, xm1 = 0.f;
    if (lc >= 3) {
        xm3 = b2f(p[(size_t)(lc - 3) * S]);
        xm2 = b2f(p[(size_t)(lc - 2) * S]);
        xm1 = b2f(p[(size_t)(lc - 1) * S]);
    }
    for (int l = lc; l < lc + 256; ++l) {
        float x0 = b2f(p[(size_t)l * S]);
        float a = w0 * xm3 + w1 * xm2 + w2 * xm1 + w3 * x0;
        xc[(size_t)l * DINNER + d] = f2b(a / (1.0f + __expf(-a)));
        xm3 = xm2; xm2 = xm1; xm1 = x0;
    }
}

// ---- conv, serial in-place fallback ----
__global__ __launch_bounds__(256) void conv_silu_inplace(
    bf16* __restrict__ xz, const float* __restrict__ w)
{
    const int d = blockIdx.x * 256 + threadIdx.x;
    const float w0 = w[d * 4 + 0];
    const float w1 = w[d * 4 + 1];
    const float w2 = w[d * 4 + 2];
    const float w3 = w[d * 4 + 3];
    bf16* p = xz + d;
    const size_t S = 2 * DINNER;
    float xm3 = 0.f, xm2 = 0.f, xm1 = 0.f;
    for (int l = 0; l < LSEQ; l += 4) {
        float x0 = b2f(p[(size_t)(l + 0) * S]);
        float x1 = b2f(p[(size_t)(l + 1) * S]);
        float x2 = b2f(p[(size_t)(l + 2) * S]);
        float x3 = b2f(p[(size_t)(l + 3) * S]);
        float a0 = w0 * xm3 + w1 * xm2 + w2 * xm1 + w3 * x0;
        float a1 = w0 * xm2 + w1 * xm1 + w2 * x0  + w3 * x1;
        float a2 = w0 * xm1 + w1 * x0  + w2 * x1  + w3 * x2;
        float a3 = w0 * x0  + w1 * x1  + w2 * x2  + w3 * x3;
        p[(size_t)(l + 0) * S] = f2b(a0 / (1.0f + __expf(-a0)));
        p[(size_t)(l + 1) * S] = f2b(a1 / (1.0f + __expf(-a1)));
        p[(size_t)(l + 2) * S] = f2b(a2 / (1.0f + __expf(-a2)));
        p[(size_t)(l + 3) * S] = f2b(a3 / (1.0f + __expf(-a3)));
        xm3 = x1; xm2 = x2; xm1 = x3;
    }
}

// ---- chunked scan pass 1 ----
__global__ __launch_bounds__(256) void scan_chunk1(
    const float* __restrict__ dlt, const bf16* __restrict__ xc,
    const bf16* __restrict__ xdbl, const float* __restrict__ A_log,
    float* __restrict__ hend, float* __restrict__ Pbuf)
{
    const int nq = threadIdx.x & 3;
    const int d  = blockIdx.x * 64 + (threadIdx.x >> 2);
    const int c  = blockIdx.y;

    float Ac[4];
#pragma unroll
    for (int i = 0; i < 4; i++)
        Ac[i] = -__expf(A_log[d * DSTATE + nq * 4 + i]);

    float h[4] = {0.f, 0.f, 0.f, 0.f};
    float P[4] = {1.f, 1.f, 1.f, 1.f};
    for (int l = c * LCHUNK; l < (c + 1) * LCHUNK; ++l) {
        const float delta = dlt[(size_t)l * DINNER + d];
        const float u     = b2f(xc[(size_t)l * DINNER + d]);
        const uint2 qb = *(const uint2*)(xdbl + (size_t)l * DXP + DTRANK + nq * 4);
        float Bv[4] = { bl16(qb.x), bh16(qb.x), bl16(qb.y), bh16(qb.y) };
        const float du = delta * u;
#pragma unroll
        for (int i = 0; i < 4; i++) {
            float dA = __expf(delta * Ac[i]);
            h[i] = h[i] * dA + du * Bv[i];
            P[i] *= dA;
        }
    }
    size_t idx = ((size_t)c * DINNER + d) * DSTATE + nq * 4;
    float4v hv; hv[0] = h[0]; hv[1] = h[1]; hv[2] = h[2]; hv[3] = h[3];
    float4v pv; pv[0] = P[0]; pv[1] = P[1]; pv[2] = P[2]; pv[3] = P[3];
    *(float4v*)(hend + idx) = hv;
    *(float4v*)(Pbuf + idx) = pv;
}

// ---- combine ----
__global__ __launch_bounds__(256) void scan_combine(
    float* __restrict__ hend, const float* __restrict__ Pbuf)
{
    const int dn = blockIdx.x * 256 + threadIdx.x;
    float H = 0.f;
    for (int c = 0; c < NCHUNK; ++c) {
        size_t idx = (size_t)c * (DINNER * DSTATE) + dn;
        float he = hend[idx];
        float p  = Pbuf[idx];
        hend[idx] = H;
        H = he + p * H;
    }
}

// ---- pass 3 ----
__global__ __launch_bounds__(256) void scan_chunk2(
    const float* __restrict__ dlt, const bf16* __restrict__ xc,
    bf16* __restrict__ xz, const bf16* __restrict__ xdbl,
    const float* __restrict__ A_log, const float* __restrict__ Dp,
    const float* __restrict__ Hin)
{
    const int nq = threadIdx.x & 3;
    const int d  = blockIdx.x * 64 + (threadIdx.x >> 2);
    const int c  = blockIdx.y;

    float Ac[4];
#pragma unroll
    for (int i = 0; i < 4; i++)
        Ac[i] = -__expf(A_log[d * DSTATE + nq * 4 + i]);
    const float Dv = Dp[d];

    float h[4];
    {
        float4v hv = *(const float4v*)(Hin + ((size_t)c * DINNER + d) * DSTATE + nq * 4);
        h[0] = hv[0]; h[1] = hv[1]; h[2] = hv[2]; h[3] = hv[3];
    }
    for (int l = c * LCHUNK; l < (c + 1) * LCHUNK; ++l) {
        const float delta = dlt[(size_t)l * DINNER + d];
        const float u     = b2f(xc[(size_t)l * DINNER + d]);
        const uint2 qb = *(const uint2*)(xdbl + (size_t)l * DXP + DTRANK + nq * 4);
        const uint2 qc = *(const uint2*)(xdbl + (size_t)l * DXP + DTRANK + DSTATE + nq * 4);
        float Bv[4] = { bl16(qb.x), bh16(qb.x), bl16(qb.y), bh16(qb.y) };
        float Cv[4] = { bl16(qc.x), bh16(qc.x), bl16(qc.y), bh16(qc.y) };
        const float du = delta * u;
        float yv = 0.f;
#pragma unroll
        for (int i = 0; i < 4; i++) {
            float dA = __expf(delta * Ac[i]);
            h[i] = h[i] * dA + du * Bv[i];
            yv += h[i] * Cv[i];
        }
        yv += __shfl_xor(yv, 1);
        yv += __shfl_xor(yv, 2);
        if (nq == 0) {
            yv += u * Dv;
            bf16* zp = xz + (size_t)l * (2 * DINNER) + DINNER + d;
            float z = b2f(*zp);
            yv *= z / (1.0f + __expf(-z));
            *zp = f2b(yv);
        }
    }
}

// ---- serial scan fallback ----
template<typename DT>
__global__ __launch_bounds__(256) void scan_serial(
    const DT* __restrict__ dlt, bf16* __restrict__ xz,
    const bf16* __restrict__ xdbl,
    const float* __restrict__ A_log, const float* __restrict__ Dp)
{
    const int nq = threadIdx.x & 3;
    const int d  = blockIdx.x * 64 + (threadIdx.x >> 2);
    float Ac[4];
#pragma unroll
    for (int i = 0; i < 4; i++)
        Ac[i] = -__expf(A_log[d * DSTATE + nq * 4 + i]);
    const float Dv = Dp[d];
    float h[4] = {0.f, 0.f, 0.f, 0.f};
    for (int l = 0; l < LSEQ; ++l) {
        const float delta = cvtL<DT>(dlt[(size_t)l * DINNER + d]);
        const float u     = b2f(xz[(size_t)l * (2 * DINNER) + d]);
        const uint2 qb = *(const uint2*)(xdbl + (size_t)l * DXP + DTRANK + nq * 4);
        const uint2 qc = *(const uint2*)(xdbl + (size_t)l * DXP + DTRANK + DSTATE + nq * 4);
        float Bv[4] = { bl16(qb.x), bh16(qb.x), bl16(qb.y), bh16(qb.y) };
        float Cv[4] = { bl16(qc.x), bh16(qc.x), bl16(qc.y), bh16(qc.y) };
        const float du = delta * u;
        float yv = 0.f;
#pragma unroll
        for (int i = 0; i < 4; i++) {
            float dA = __expf(delta * Ac[i]);
            h[i] = h[i] * dA + du * Bv[i];
            yv += h[i] * Cv[i];
        }
        yv += __shfl_xor(yv, 1);
        yv += __shfl_xor(yv, 2);
        if (nq == 0) {
            yv += u * Dv;
            bf16* zp = xz + (size_t)l * (2 * DINNER) + DINNER + d;
            float z = b2f(*zp);
            yv *= z / (1.0f + __expf(-z));
            *zp = f2b(yv);
        }
    }
}

extern "C" void kernel_launch(void* const* d_in, const int* in_sizes, int n_in,
                              void* d_out, int out_size, void* d_ws, size_t ws_size,
                              hipStream_t stream)
{
    // Inputs FLOAT32, setup_inputs() dict order.
    const float* hs      = (const float*)d_in[0];
    const float* w_in    = (const float*)d_in[1];
    const float* w_conv  = (const float*)d_in[2];
    const float* w_xproj = (const float*)d_in[3];
    const float* w_dt    = (const float*)d_in[4];
    const float *w_out, *b_dt, *A_log, *Dp;
    if (in_sizes[5] == DMODEL * DINNER) {
        w_out = (const float*)d_in[5];
        b_dt  = (const float*)d_in[6];
        A_log = (const float*)d_in[7];
        Dp    = (const float*)d_in[8];
    } else {
        b_dt  = (const float*)d_in[5];
        A_log = (const float*)d_in[6];
        Dp    = (const float*)d_in[7];
        w_out = (const float*)d_in[8];
    }
    float* out = (float*)d_out;

    const size_t SZ_XZ   = (size_t)LSEQ * 2 * DINNER * sizeof(bf16);         // 33.5 MB
    const size_t SZ_XC   = (size_t)LSEQ * DINNER * sizeof(bf16);             // 16.8 MB
    const size_t SZ_XDBL = (size_t)LSEQ * DXP * sizeof(bf16);                //  0.7 MB
    const size_t SZ_DLTF = (size_t)LSEQ * DINNER * sizeof(float);            // 33.5 MB
    const size_t SZ_HP   = (size_t)NCHUNK * DINNER * DSTATE * sizeof(float); // 16.8 MB

    char* p = (char*)d_ws;
    bf16* xz = (bf16*)p; p += SZ_XZ;

    const size_t need_fast = SZ_XZ + SZ_XC + SZ_XDBL + SZ_DLTF + 2 * SZ_HP; // 118 MB
    const bool fast = ws_size >= need_fast;

    dim3 blk(256);

    if (fast) {
        bf16*  xc   = (bf16*)p;  p += SZ_XC;
        bf16*  xdbl = (bf16*)p;  p += SZ_XDBL;
        char*  hpr  = p;         p += SZ_DLTF;   // dlt fp32 region (after in_proj)
        char*  dreg = p;                          // hend+Pbuf region (after dt_proj)
        float* dlt  = (float*)hpr;
        float* hend = (float*)dreg;
        float* Pbuf = (float*)(dreg + SZ_HP);

        // time-aliased bf16 copies (stream-serial => safe):
        bf16* w_in_b  = (bf16*)hpr;               // dead after in_proj (dlt overwrites)
        bf16* hs_b    = (bf16*)dreg;              // dead after in_proj (hend overwrites)
        bf16* w_dt_b  = (bf16*)(dreg + (size_t)LSEQ * DMODEL * sizeof(bf16)); // after hs_b
        bf16* w_out_b = (bf16*)xc;                // written after scan, xc dead by then

        // 0) one fused convert: w_in -> w_in_b, hs -> hs_b, w_dt -> w_dt_b
        {
            int n0 = 2 * DINNER * DMODEL, n1 = LSEQ * DMODEL, n2 = DINNER * DTRANK;
            cvt3<<<dim3((n0 + n1 + n2) / 2048), blk, 0, stream>>>(
                w_in, w_in_b, n0, hs, hs_b, n1, w_dt, w_dt_b, n2);
        }

        // 1) in_proj (BK=64 glds)
        gemm_glds64<128, bf16, false><<<dim3(LSEQ/128, (2*DINNER)/128), blk, 0, stream>>>(
            hs_b, DMODEL, w_in_b, DMODEL, xz, 2*DINNER, DMODEL, nullptr);

        // 2) conv + silu -> xc
        conv_silu_par<<<dim3(DINNER/256, LSEQ/256), blk, 0, stream>>>(xz, w_conv, xc);

        // 3) x_proj (N=160, guarded 64-tile)
        gemm_bt<bf16, bf16, false><<<dim3(LSEQ/64, 3), blk, 0, stream>>>(
            xc, DINNER, w_xproj, DINNER, xdbl, DXP, LSEQ, DXP, DINNER, nullptr);

        // 4) dt_proj + softplus -> dlt fp32 (hpr; w_in_b dead)
        gemm_glds64<128, float, true><<<dim3(LSEQ/128, DINNER/128), blk, 0, stream>>>(
            xdbl, DXP, w_dt_b, DTRANK, dlt, DINNER, DTRANK, b_dt);

        // 5) chunk-parallel scan (hend/Pbuf overwrite hs_b/w_dt_b; both dead)
        scan_chunk1<<<dim3(DINNER/64, NCHUNK), blk, 0, stream>>>(
            dlt, xc, xdbl, A_log, hend, Pbuf);
        scan_combine<<<dim3(DINNER*DSTATE/256), blk, 0, stream>>>(hend, Pbuf);
        scan_chunk2<<<dim3(DINNER/64, NCHUNK), blk, 0, stream>>>(
            dlt, xc, xz, xdbl, A_log, Dp, hend);

        // 6) out_proj (BN=64 -> 512 blocks; xc dead, reuse for w_out_b)
        cvt1<<<dim3((DMODEL*DINNER)/2048), blk, 0, stream>>>(w_out, w_out_b, DMODEL*DINNER);
        gemm_glds64<64, float, false><<<dim3(LSEQ/128, DMODEL/64), blk, 0, stream>>>(
            xz + DINNER, 2*DINNER, w_out_b, DINNER, out, DMODEL, DINNER, nullptr);
    } else {
        // fallback tiers: R4 layout (in-place conv + serial scan, fp32-B gemms)
        bf16* xdbl = (bf16*)p; p += SZ_XDBL;
        size_t used = (size_t)(p - (char*)d_ws);
        bool dlt_f32 = (ws_size - used) >= SZ_DLTF;

        gemm_bt<float, bf16, false><<<dim3(LSEQ/64, (2*DINNER)/64), blk, 0, stream>>>(
            hs, DMODEL, w_in, DMODEL, xz, 2*DINNER, LSEQ, 2*DINNER, DMODEL, nullptr);
        conv_silu_inplace<<<dim3(DINNER/256), blk, 0, stream>>>(xz, w_conv);
        gemm_bt<bf16, bf16, false><<<dim3(LSEQ/64, 3), blk, 0, stream>>>(
            xz, 2*DINNER, w_xproj, DINNER, xdbl, DXP, LSEQ, DXP, DINNER, nullptr);
        if (dlt_f32) {
            float* dlt = (float*)p;
            gemm_bt<bf16, float, true><<<dim3(LSEQ/64, DINNER/64), blk, 0, stream>>>(
                xdbl, DXP, w_dt, DTRANK, dlt, DINNER, LSEQ, DINNER, DTRANK, b_dt);
            scan_serial<float><<<dim3(DINNER/64), blk, 0, stream>>>(dlt, xz, xdbl, A_log, Dp);
        } else {
            bf16* dlt = (bf16*)p;
            gemm_bt<bf16, bf16, true><<<dim3(LSEQ/64, DINNER/64), blk, 0, stream>>>(
                xdbl, DXP, w_dt, DTRANK, dlt, DINNER, LSEQ, DINNER, DTRANK, b_dt);
            scan_serial<bf16><<<dim3(DINNER/64), blk, 0, stream>>>(dlt, xz, xdbl, A_log, Dp);
        }
        gemm_bt<bf16, float, false><<<dim3(LSEQ/64, DMODEL/64), blk, 0, stream>>>(
            xz + DINNER, 2*DINNER, w_out, DINNER, out, DMODEL, LSEQ, DMODEL, DINNER, nullptr);
    }
}

// Round 8
// 523.911 us; speedup vs baseline: 4.5412x; 1.1473x over previous
//
#include <hip/hip_runtime.h>
#include <hip/hip_bf16.h>

#define LSEQ 2048
#define DMODEL 2048
#define DINNER 4096
#define DSTATE 16
#define DTRANK 128
#define DCONV 4
#define DXP (DTRANK + 2*DSTATE)   // 160
#define NCHUNK 64
#define LCHUNK (LSEQ / NCHUNK)    // 32
#define KSPLIT 16

using bf16 = __hip_bfloat16;
typedef __attribute__((ext_vector_type(8))) short short8;
typedef __attribute__((ext_vector_type(4))) float float4v;

__device__ __forceinline__ float b2f(bf16 v) { return __bfloat162float(v); }
__device__ __forceinline__ bf16 f2b(float v) { return __float2bfloat16(v); }
__device__ __forceinline__ float bl16(unsigned u) { return __uint_as_float(u << 16); }
__device__ __forceinline__ float bh16(unsigned u) { return __uint_as_float(u & 0xffff0000u); }

__device__ __forceinline__ short f2bs(float v) {
    bf16 b = __float2bfloat16(v);
    union { bf16 b; short s; } u; u.b = b; return u.s;
}

__device__ __forceinline__ short8 ld8(const float* p) {
    float4v f0 = *(const float4v*)p;
    float4v f1 = *(const float4v*)(p + 4);
    short8 r;
    r[0] = f2bs(f0[0]); r[1] = f2bs(f0[1]); r[2] = f2bs(f0[2]); r[3] = f2bs(f0[3]);
    r[4] = f2bs(f1[0]); r[5] = f2bs(f1[1]); r[6] = f2bs(f1[2]); r[7] = f2bs(f1[3]);
    return r;
}
__device__ __forceinline__ short8 ld8(const bf16* p) { return *(const short8*)p; }

template<typename CT> __device__ __forceinline__ CT cvtC(float v);
template<> __device__ __forceinline__ bf16  cvtC<bf16>(float v)  { return f2b(v); }
template<> __device__ __forceinline__ float cvtC<float>(float v) { return v; }

template<typename T> __device__ __forceinline__ float cvtL(T v);
template<> __device__ __forceinline__ float cvtL<bf16>(bf16 v)   { return b2f(v); }
template<> __device__ __forceinline__ float cvtL<float>(float v) { return v; }

// async global->LDS, 16 B per lane, dest = wave-uniform base + lane*16
__device__ __forceinline__ void glds16(const bf16* g, void* lds_base) {
    __builtin_amdgcn_global_load_lds(
        (const __attribute__((address_space(1))) void*)g,
        (__attribute__((address_space(3))) void*)lds_base, 16, 0, 0);
}

// ---- fused fp32->bf16 convert of three arrays (each n % 2048 == 0) ----
__global__ __launch_bounds__(256) void cvt3(
    const float* __restrict__ s0, bf16* __restrict__ d0, int n0,
    const float* __restrict__ s1, bf16* __restrict__ d1, int n1,
    const float* __restrict__ s2, bf16* __restrict__ d2, int n2)
{
    const int b = blockIdx.x;
    const int nb0 = n0 >> 11, nb1 = n1 >> 11;
    const float* s; bf16* d; int i;
    if (b < nb0)            { s = s0; d = d0; i = b * 2048; }
    else if (b < nb0 + nb1) { s = s1; d = d1; i = (b - nb0) * 2048; }
    else                    { s = s2; d = d2; i = (b - nb0 - nb1) * 2048; }
    i += threadIdx.x * 8;
    *(short8*)(d + i) = ld8(s + i);
}

__global__ __launch_bounds__(256) void cvt1(
    const float* __restrict__ src, bf16* __restrict__ dst, int n)
{
    int i = (blockIdx.x * 256 + threadIdx.x) * 8;
    if (i >= n) return;
    *(short8*)(dst + i) = ld8(src + i);
}

// ============================================================================
// BK=64 glds GEMM: C[m][n] = sum_k A[m][k]*B[n][k], all-bf16 inputs.
// 128 x BN tile, BK=64, XOR-16B LDS swizzle. 4 waves, 32 MFMA/wave per K-iter.
// REQUIRES: M%128==0, N%BN==0, K%64==0.
// ============================================================================
template<int BN, typename CT, bool SP>
__global__ __launch_bounds__(256) void gemm_glds64(
    const bf16* __restrict__ A, int lda,
    const bf16* __restrict__ B, int ldb,
    CT* __restrict__ C, int ldc,
    int K, const float* __restrict__ bias)
{
    constexpr int NJ  = BN / 32;
    constexpr int BGL = BN / 32;
    __shared__ bf16 As[128][64];
    __shared__ bf16 Bs[BN][64];

    const int t    = threadIdx.x;
    const int wave = t >> 6;
    const int lane = t & 63;
    const int t16  = lane & 15;
    const int quad = lane >> 4;
    const int wm   = (wave >> 1) * 64;
    const int wn   = (wave & 1) * (BN / 2);
    const int bm0  = blockIdx.x * 128;
    const int bn0  = blockIdx.y * BN;

    const int lrow = lane >> 3;
    const int gseg = (((lane & 7) ^ lrow) * 8);

    const bf16* Ag[4]; char* Ad[4];
#pragma unroll
    for (int g = 0; g < 4; g++) {
        Ag[g] = A + (size_t)(bm0 + wave * 32 + g * 8 + lrow) * lda + gseg;
        Ad[g] = (char*)As + (wave * 32 + g * 8) * 128;
    }
    const bf16* Bg[BGL]; char* Bd[BGL];
#pragma unroll
    for (int g = 0; g < BGL; g++) {
        int r = (BN == 128) ? (wave * 32 + g * 8) : (wave * 16 + g * 8);
        Bg[g] = B + (size_t)(bn0 + r + lrow) * ldb + gseg;
        Bd[g] = (char*)Bs + r * 128;
    }

    float4v acc[4][NJ];
#pragma unroll
    for (int i = 0; i < 4; i++)
#pragma unroll
        for (int j = 0; j < NJ; j++) acc[i][j] = (float4v)(0.0f);

    const int sw = t16 & 7;

    for (int k0 = 0; k0 < K; k0 += 64) {
        __syncthreads();
#pragma unroll
        for (int g = 0; g < 4; g++)   glds16(Ag[g] + k0, Ad[g]);
#pragma unroll
        for (int g = 0; g < BGL; g++) glds16(Bg[g] + k0, Bd[g]);
        __syncthreads();

#pragma unroll
        for (int kk = 0; kk < 2; kk++) {
            const int kso = ((kk * 4 + quad) ^ sw) * 8;
            short8 a[4], b[NJ];
#pragma unroll
            for (int mi = 0; mi < 4; mi++)
                a[mi] = *(const short8*)(&As[wm + mi * 16 + t16][kso]);
#pragma unroll
            for (int nj = 0; nj < NJ; nj++)
                b[nj] = *(const short8*)(&Bs[wn + nj * 16 + t16][kso]);
#pragma unroll
            for (int mi = 0; mi < 4; mi++)
#pragma unroll
                for (int nj = 0; nj < NJ; nj++)
                    acc[mi][nj] = __builtin_amdgcn_mfma_f32_16x16x32_bf16(
                        a[mi], b[nj], acc[mi][nj], 0, 0, 0);
        }
    }

#pragma unroll
    for (int mi = 0; mi < 4; mi++) {
#pragma unroll
        for (int nj = 0; nj < NJ; nj++) {
            int n_g = bn0 + wn + nj * 16 + t16;
            float bia = SP ? bias[n_g] : 0.0f;
#pragma unroll
            for (int r = 0; r < 4; r++) {
                int m_g = bm0 + wm + mi * 16 + quad * 4 + r;
                float v = acc[mi][nj][r];
                if (SP) {
                    float x = v + bia;
                    v = (x > 20.0f) ? x : log1pf(__expf(x));
                }
                C[(size_t)m_g * ldc + n_g] = cvtC<CT>(v);
            }
        }
    }
}

// ---- guarded 64x64 GEMM (fallback tiers); B is fp32 ----
template<typename AT, typename CT, bool SP>
__global__ __launch_bounds__(256) void gemm_bt(
    const AT* __restrict__ A, int lda,
    const float* __restrict__ B, int ldb,
    CT* __restrict__ C, int ldc,
    int M, int N, int K,
    const float* __restrict__ bias)
{
    __shared__ bf16 As[64][40];
    __shared__ bf16 Bs[64][40];

    const int t    = threadIdx.x;
    const int bm0  = blockIdx.x * 64;
    const int bn0  = blockIdx.y * 64;
    const int row  = t >> 2;
    const int seg  = (t & 3) * 8;
    const int wave = t >> 6;
    const int lane = t & 63;
    const int wm   = (wave >> 1) * 32;
    const int wn   = (wave & 1) * 32;
    const int t16  = lane & 15;
    const int quad = lane >> 4;

    float4v acc[2][2];
#pragma unroll
    for (int i = 0; i < 2; i++)
#pragma unroll
        for (int j = 0; j < 2; j++) acc[i][j] = (float4v)(0.0f);

    const AT*    Aptr = A + (size_t)(bm0 + row) * lda + seg;
    const float* Bptr = B + (size_t)(bn0 + row) * ldb + seg;
    const bool a_ok = (bm0 + row) < M;
    const bool b_ok = (bn0 + row) < N;
    const short8 zero8 = (short8)(0);

    for (int k0 = 0; k0 < K; k0 += 32) {
        short8 av = a_ok ? ld8(Aptr + k0) : zero8;
        short8 bv = b_ok ? ld8(Bptr + k0) : zero8;
        __syncthreads();
        *(short8*)(&As[row][seg]) = av;
        *(short8*)(&Bs[row][seg]) = bv;
        __syncthreads();

        short8 a0 = *(const short8*)(&As[wm + t16][quad * 8]);
        short8 a1 = *(const short8*)(&As[wm + 16 + t16][quad * 8]);
        short8 b0 = *(const short8*)(&Bs[wn + t16][quad * 8]);
        short8 b1 = *(const short8*)(&Bs[wn + 16 + t16][quad * 8]);
        acc[0][0] = __builtin_amdgcn_mfma_f32_16x16x32_bf16(a0, b0, acc[0][0], 0, 0, 0);
        acc[0][1] = __builtin_amdgcn_mfma_f32_16x16x32_bf16(a0, b1, acc[0][1], 0, 0, 0);
        acc[1][0] = __builtin_amdgcn_mfma_f32_16x16x32_bf16(a1, b0, acc[1][0], 0, 0, 0);
        acc[1][1] = __builtin_amdgcn_mfma_f32_16x16x32_bf16(a1, b1, acc[1][1], 0, 0, 0);
    }

#pragma unroll
    for (int i = 0; i < 2; i++) {
#pragma unroll
        for (int j = 0; j < 2; j++) {
            int n_g = bn0 + wn + j * 16 + t16;
            if (n_g >= N) continue;
            float bia = SP ? bias[n_g] : 0.0f;
#pragma unroll
            for (int r = 0; r < 4; r++) {
                int m_g = bm0 + wm + i * 16 + quad * 4 + r;
                if (m_g >= M) continue;
                float v = acc[i][j][r];
                if (SP) {
                    float x = v + bia;
                    v = (x > 20.0f) ? x : log1pf(__expf(x));
                }
                C[(size_t)m_g * ldc + n_g] = cvtC<CT>(v);
            }
        }
    }
}

// ---- split-K 64x64 GEMM for tall-skinny x_proj: fp32 partials ----
// grid (M/64, ceil(N/64), KS); each block covers K range [z*K/KS,(z+1)*K/KS)
__global__ __launch_bounds__(256) void gemm_bt_splitk(
    const bf16* __restrict__ A, int lda,
    const float* __restrict__ B, int ldb,
    float* __restrict__ P,            // [KS][M][N]
    int M, int N, int K)
{
    __shared__ bf16 As[64][40];
    __shared__ bf16 Bs[64][40];

    const int t    = threadIdx.x;
    const int bm0  = blockIdx.x * 64;
    const int bn0  = blockIdx.y * 64;
    const int ks   = blockIdx.z;
    const int KS   = gridDim.z;
    const int kbeg = ks * (K / KS);
    const int kend = kbeg + (K / KS);
    const int row  = t >> 2;
    const int seg  = (t & 3) * 8;
    const int wave = t >> 6;
    const int lane = t & 63;
    const int wm   = (wave >> 1) * 32;
    const int wn   = (wave & 1) * 32;
    const int t16  = lane & 15;
    const int quad = lane >> 4;

    float4v acc[2][2];
#pragma unroll
    for (int i = 0; i < 2; i++)
#pragma unroll
        for (int j = 0; j < 2; j++) acc[i][j] = (float4v)(0.0f);

    const bf16*  Aptr = A + (size_t)(bm0 + row) * lda + seg;
    const float* Bptr = B + (size_t)(bn0 + row) * ldb + seg;
    const bool a_ok = (bm0 + row) < M;
    const bool b_ok = (bn0 + row) < N;
    const short8 zero8 = (short8)(0);

    for (int k0 = kbeg; k0 < kend; k0 += 32) {
        short8 av = a_ok ? ld8(Aptr + k0) : zero8;
        short8 bv = b_ok ? ld8(Bptr + k0) : zero8;
        __syncthreads();
        *(short8*)(&As[row][seg]) = av;
        *(short8*)(&Bs[row][seg]) = bv;
        __syncthreads();

        short8 a0 = *(const short8*)(&As[wm + t16][quad * 8]);
        short8 a1 = *(const short8*)(&As[wm + 16 + t16][quad * 8]);
        short8 b0 = *(const short8*)(&Bs[wn + t16][quad * 8]);
        short8 b1 = *(const short8*)(&Bs[wn + 16 + t16][quad * 8]);
        acc[0][0] = __builtin_amdgcn_mfma_f32_16x16x32_bf16(a0, b0, acc[0][0], 0, 0, 0);
        acc[0][1] = __builtin_amdgcn_mfma_f32_16x16x32_bf16(a0, b1, acc[0][1], 0, 0, 0);
        acc[1][0] = __builtin_amdgcn_mfma_f32_16x16x32_bf16(a1, b0, acc[1][0], 0, 0, 0);
        acc[1][1] = __builtin_amdgcn_mfma_f32_16x16x32_bf16(a1, b1, acc[1][1], 0, 0, 0);
    }

    float* Pk = P + (size_t)ks * M * N;
#pragma unroll
    for (int i = 0; i < 2; i++) {
#pragma unroll
        for (int j = 0; j < 2; j++) {
            int n_g = bn0 + wn + j * 16 + t16;
            if (n_g >= N) continue;
#pragma unroll
            for (int r = 0; r < 4; r++) {
                int m_g = bm0 + wm + i * 16 + quad * 4 + r;
                if (m_g >= M) continue;
                Pk[(size_t)m_g * N + n_g] = acc[i][j][r];
            }
        }
    }
}

// ---- sum KS fp32 partials -> bf16 ----
__global__ __launch_bounds__(256) void reduce_splitk(
    const float* __restrict__ P, bf16* __restrict__ C, int MN)
{
    int i = blockIdx.x * 256 + threadIdx.x;
    if (i >= MN) return;
    float s = 0.f;
#pragma unroll
    for (int ks = 0; ks < KSPLIT; ks++) s += P[(size_t)ks * MN + i];
    C[i] = f2b(s);
}

// ---- conv, L-parallel: reads xz (x-half), writes xc ----
__global__ __launch_bounds__(256) void conv_silu_par(
    const bf16* __restrict__ xz, const float* __restrict__ w, bf16* __restrict__ xc)
{
    const int d  = blockIdx.x * 256 + threadIdx.x;
    const int lc = blockIdx.y * 256;
    const float w0 = w[d * 4 + 0];
    const float w1 = w[d * 4 + 1];
    const float w2 = w[d * 4 + 2];
    const float w3 = w[d * 4 + 3];
    const size_t S = 2 * DINNER;
    const bf16* p = xz + d;
    float xm3 = 0.f, xm2 = 0.f, xm1 = 0.f;
    if (lc >= 3) {
        xm3 = b2f(p[(size_t)(lc - 3) * S]);
        xm2 = b2f(p[(size_t)(lc - 2) * S]);
        xm1 = b2f(p[(size_t)(lc - 1) * S]);
    }
    for (int l = lc; l < lc + 256; ++l) {
        float x0 = b2f(p[(size_t)l * S]);
        float a = w0 * xm3 + w1 * xm2 + w2 * xm1 + w3 * x0;
        xc[(size_t)l * DINNER + d] = f2b(a / (1.0f + __expf(-a)));
        xm3 = xm2; xm2 = xm1; xm1 = x0;
    }
}

// ---- conv, serial in-place fallback ----
__global__ __launch_bounds__(256) void conv_silu_inplace(
    bf16* __restrict__ xz, const float* __restrict__ w)
{
    const int d = blockIdx.x * 256 + threadIdx.x;
    const float w0 = w[d * 4 + 0];
    const float w1 = w[d * 4 + 1];
    const float w2 = w[d * 4 + 2];
    const float w3 = w[d * 4 + 3];
    bf16* p = xz + d;
    const size_t S = 2 * DINNER;
    float xm3 = 0.f, xm2 = 0.f, xm1 = 0.f;
    for (int l = 0; l < LSEQ; l += 4) {
        float x0 = b2f(p[(size_t)(l + 0) * S]);
        float x1 = b2f(p[(size_t)(l + 1) * S]);
        float x2 = b2f(p[(size_t)(l + 2) * S]);
        float x3 = b2f(p[(size_t)(l + 3) * S]);
        float a0 = w0 * xm3 + w1 * xm2 + w2 * xm1 + w3 * x0;
        float a1 = w0 * xm2 + w1 * xm1 + w2 * x0  + w3 * x1;
        float a2 = w0 * xm1 + w1 * x0  + w2 * x1  + w3 * x2;
        float a3 = w0 * x0  + w1 * x1  + w2 * x2  + w3 * x3;
        p[(size_t)(l + 0) * S] = f2b(a0 / (1.0f + __expf(-a0)));
        p[(size_t)(l + 1) * S] = f2b(a1 / (1.0f + __expf(-a1)));
        p[(size_t)(l + 2) * S] = f2b(a2 / (1.0f + __expf(-a2)));
        p[(size_t)(l + 3) * S] = f2b(a3 / (1.0f + __expf(-a3)));
        xm3 = x1; xm2 = x2; xm1 = x3;
    }
}

// ---- chunked scan pass 1 ----
__global__ __launch_bounds__(256) void scan_chunk1(
    const float* __restrict__ dlt, const bf16* __restrict__ xc,
    const bf16* __restrict__ xdbl, const float* __restrict__ A_log,
    float* __restrict__ hend, float* __restrict__ Pbuf)
{
    const int nq = threadIdx.x & 3;
    const int d  = blockIdx.x * 64 + (threadIdx.x >> 2);
    const int c  = blockIdx.y;

    float Ac[4];
#pragma unroll
    for (int i = 0; i < 4; i++)
        Ac[i] = -__expf(A_log[d * DSTATE + nq * 4 + i]);

    float h[4] = {0.f, 0.f, 0.f, 0.f};
    float P[4] = {1.f, 1.f, 1.f, 1.f};
    for (int l = c * LCHUNK; l < (c + 1) * LCHUNK; ++l) {
        const float delta = dlt[(size_t)l * DINNER + d];
        const float u     = b2f(xc[(size_t)l * DINNER + d]);
        const uint2 qb = *(const uint2*)(xdbl + (size_t)l * DXP + DTRANK + nq * 4);
        float Bv[4] = { bl16(qb.x), bh16(qb.x), bl16(qb.y), bh16(qb.y) };
        const float du = delta * u;
#pragma unroll
        for (int i = 0; i < 4; i++) {
            float dA = __expf(delta * Ac[i]);
            h[i] = h[i] * dA + du * Bv[i];
            P[i] *= dA;
        }
    }
    size_t idx = ((size_t)c * DINNER + d) * DSTATE + nq * 4;
    float4v hv; hv[0] = h[0]; hv[1] = h[1]; hv[2] = h[2]; hv[3] = h[3];
    float4v pv; pv[0] = P[0]; pv[1] = P[1]; pv[2] = P[2]; pv[3] = P[3];
    *(float4v*)(hend + idx) = hv;
    *(float4v*)(Pbuf + idx) = pv;
}

// ---- combine ----
__global__ __launch_bounds__(256) void scan_combine(
    float* __restrict__ hend, const float* __restrict__ Pbuf)
{
    const int dn = blockIdx.x * 256 + threadIdx.x;
    float H = 0.f;
    for (int c = 0; c < NCHUNK; ++c) {
        size_t idx = (size_t)c * (DINNER * DSTATE) + dn;
        float he = hend[idx];
        float p  = Pbuf[idx];
        hend[idx] = H;
        H = he + p * H;
    }
}

// ---- pass 3 ----
__global__ __launch_bounds__(256) void scan_chunk2(
    const float* __restrict__ dlt, const bf16* __restrict__ xc,
    bf16* __restrict__ xz, const bf16* __restrict__ xdbl,
    const float* __restrict__ A_log, const float* __restrict__ Dp,
    const float* __restrict__ Hin)
{
    const int nq = threadIdx.x & 3;
    const int d  = blockIdx.x * 64 + (threadIdx.x >> 2);
    const int c  = blockIdx.y;

    float Ac[4];
#pragma unroll
    for (int i = 0; i < 4; i++)
        Ac[i] = -__expf(A_log[d * DSTATE + nq * 4 + i]);
    const float Dv = Dp[d];

    float h[4];
    {
        float4v hv = *(const float4v*)(Hin + ((size_t)c * DINNER + d) * DSTATE + nq * 4);
        h[0] = hv[0]; h[1] = hv[1]; h[2] = hv[2]; h[3] = hv[3];
    }
    for (int l = c * LCHUNK; l < (c + 1) * LCHUNK; ++l) {
        const float delta = dlt[(size_t)l * DINNER + d];
        const float u     = b2f(xc[(size_t)l * DINNER + d]);
        const uint2 qb = *(const uint2*)(xdbl + (size_t)l * DXP + DTRANK + nq * 4);
        const uint2 qc = *(const uint2*)(xdbl + (size_t)l * DXP + DTRANK + DSTATE + nq * 4);
        float Bv[4] = { bl16(qb.x), bh16(qb.x), bl16(qb.y), bh16(qb.y) };
        float Cv[4] = { bl16(qc.x), bh16(qc.x), bl16(qc.y), bh16(qc.y) };
        const float du = delta * u;
        float yv = 0.f;
#pragma unroll
        for (int i = 0; i < 4; i++) {
            float dA = __expf(delta * Ac[i]);
            h[i] = h[i] * dA + du * Bv[i];
            yv += h[i] * Cv[i];
        }
        yv += __shfl_xor(yv, 1);
        yv += __shfl_xor(yv, 2);
        if (nq == 0) {
            yv += u * Dv;
            bf16* zp = xz + (size_t)l * (2 * DINNER) + DINNER + d;
            float z = b2f(*zp);
            yv *= z / (1.0f + __expf(-z));
            *zp = f2b(yv);
        }
    }
}

// ---- serial scan fallback ----
template<typename DT>
__global__ __launch_bounds__(256) void scan_serial(
    const DT* __restrict__ dlt, bf16* __restrict__ xz,
    const bf16* __restrict__ xdbl,
    const float* __restrict__ A_log, const float* __restrict__ Dp)
{
    const int nq = threadIdx.x & 3;
    const int d  = blockIdx.x * 64 + (threadIdx.x >> 2);
    float Ac[4];
#pragma unroll
    for (int i = 0; i < 4; i++)
        Ac[i] = -__expf(A_log[d * DSTATE + nq * 4 + i]);
    const float Dv = Dp[d];
    float h[4] = {0.f, 0.f, 0.f, 0.f};
    for (int l = 0; l < LSEQ; ++l) {
        const float delta = cvtL<DT>(dlt[(size_t)l * DINNER + d]);
        const float u     = b2f(xz[(size_t)l * (2 * DINNER) + d]);
        const uint2 qb = *(const uint2*)(xdbl + (size_t)l * DXP + DTRANK + nq * 4);
        const uint2 qc = *(const uint2*)(xdbl + (size_t)l * DXP + DTRANK + DSTATE + nq * 4);
        float Bv[4] = { bl16(qb.x), bh16(qb.x), bl16(qb.y), bh16(qb.y) };
        float Cv[4] = { bl16(qc.x), bh16(qc.x), bl16(qc.y), bh16(qc.y) };
        const float du = delta * u;
        float yv = 0.f;
#pragma unroll
        for (int i = 0; i < 4; i++) {
            float dA = __expf(delta * Ac[i]);
            h[i] = h[i] * dA + du * Bv[i];
            yv += h[i] * Cv[i];
        }
        yv += __shfl_xor(yv, 1);
        yv += __shfl_xor(yv, 2);
        if (nq == 0) {
            yv += u * Dv;
            bf16* zp = xz + (size_t)l * (2 * DINNER) + DINNER + d;
            float z = b2f(*zp);
            yv *= z / (1.0f + __expf(-z));
            *zp = f2b(yv);
        }
    }
}

extern "C" void kernel_launch(void* const* d_in, const int* in_sizes, int n_in,
                              void* d_out, int out_size, void* d_ws, size_t ws_size,
                              hipStream_t stream)
{
    // Inputs FLOAT32, setup_inputs() dict order.
    const float* hs      = (const float*)d_in[0];
    const float* w_in    = (const float*)d_in[1];
    const float* w_conv  = (const float*)d_in[2];
    const float* w_xproj = (const float*)d_in[3];
    const float* w_dt    = (const float*)d_in[4];
    const float *w_out, *b_dt, *A_log, *Dp;
    if (in_sizes[5] == DMODEL * DINNER) {
        w_out = (const float*)d_in[5];
        b_dt  = (const float*)d_in[6];
        A_log = (const float*)d_in[7];
        Dp    = (const float*)d_in[8];
    } else {
        b_dt  = (const float*)d_in[5];
        A_log = (const float*)d_in[6];
        Dp    = (const float*)d_in[7];
        w_out = (const float*)d_in[8];
    }
    float* out = (float*)d_out;

    const size_t SZ_XZ   = (size_t)LSEQ * 2 * DINNER * sizeof(bf16);         // 33.5 MB
    const size_t SZ_XC   = (size_t)LSEQ * DINNER * sizeof(bf16);             // 16.8 MB
    const size_t SZ_XDBL = (size_t)LSEQ * DXP * sizeof(bf16);                //  0.7 MB
    const size_t SZ_DLTF = (size_t)LSEQ * DINNER * sizeof(float);            // 33.5 MB
    const size_t SZ_HP   = (size_t)NCHUNK * DINNER * DSTATE * sizeof(float); // 16.8 MB

    char* p = (char*)d_ws;
    bf16* xz = (bf16*)p; p += SZ_XZ;

    const size_t need_fast = SZ_XZ + SZ_XC + SZ_XDBL + SZ_DLTF + 2 * SZ_HP; // 118 MB
    const bool fast = ws_size >= need_fast;

    dim3 blk(256);

    if (fast) {
        bf16*  xc   = (bf16*)p;  p += SZ_XC;
        bf16*  xdbl = (bf16*)p;  p += SZ_XDBL;
        char*  hpr  = p;         p += SZ_DLTF;   // dlt fp32 region (written stage 4)
        char*  dreg = p;                          // hend+Pbuf region (written stage 5)
        float* dlt  = (float*)hpr;
        float* hend = (float*)dreg;
        float* Pbuf = (float*)(dreg + SZ_HP);

        // time-aliased buffers (stream-serial => safe):
        bf16*  w_in_b  = (bf16*)hpr;              // used stage 1; dead after
        float* xp_part = (float*)hpr;             // stage-3 split-K partials (21 MB)
        bf16*  hs_b    = (bf16*)dreg;             // used stage 1; dead after
        bf16*  w_dt_b  = (bf16*)(dreg + (size_t)LSEQ * DMODEL * sizeof(bf16));
        bf16*  w_out_b = (bf16*)xc;               // written stage 6; xc dead by then

        // 0) one fused convert: w_in, hs, w_dt -> bf16
        {
            int n0 = 2 * DINNER * DMODEL, n1 = LSEQ * DMODEL, n2 = DINNER * DTRANK;
            cvt3<<<dim3((n0 + n1 + n2) / 2048), blk, 0, stream>>>(
                w_in, w_in_b, n0, hs, hs_b, n1, w_dt, w_dt_b, n2);
        }

        // 1) in_proj (BK=64 glds)
        gemm_glds64<128, bf16, false><<<dim3(LSEQ/128, (2*DINNER)/128), blk, 0, stream>>>(
            hs_b, DMODEL, w_in_b, DMODEL, xz, 2*DINNER, DMODEL, nullptr);

        // 2) conv + silu -> xc
        conv_silu_par<<<dim3(DINNER/256, LSEQ/256), blk, 0, stream>>>(xz, w_conv, xc);

        // 3) x_proj: split-K (96 blocks was latency-bound at 104us) -> partials
        //    in hpr (w_in_b dead, dlt not yet written), then reduce -> bf16 xdbl
        gemm_bt_splitk<<<dim3(LSEQ/64, 3, KSPLIT), blk, 0, stream>>>(
            xc, DINNER, w_xproj, DINNER, xp_part, LSEQ, DXP, DINNER);
        reduce_splitk<<<dim3((LSEQ * DXP + 255) / 256), blk, 0, stream>>>(
            xp_part, xdbl, LSEQ * DXP);

        // 4) dt_proj + softplus -> dlt fp32 (overwrites xp_part; dead)
        gemm_glds64<128, float, true><<<dim3(LSEQ/128, DINNER/128), blk, 0, stream>>>(
            xdbl, DXP, w_dt_b, DTRANK, dlt, DINNER, DTRANK, b_dt);

        // 5) chunk-parallel scan (hend/Pbuf overwrite hs_b/w_dt_b; both dead)
        scan_chunk1<<<dim3(DINNER/64, NCHUNK), blk, 0, stream>>>(
            dlt, xc, xdbl, A_log, hend, Pbuf);
        scan_combine<<<dim3(DINNER*DSTATE/256), blk, 0, stream>>>(hend, Pbuf);
        scan_chunk2<<<dim3(DINNER/64, NCHUNK), blk, 0, stream>>>(
            dlt, xc, xz, xdbl, A_log, Dp, hend);

        // 6) out_proj (BN=64 -> 512 blocks; xc dead, reuse for w_out_b)
        cvt1<<<dim3((DMODEL*DINNER)/2048), blk, 0, stream>>>(w_out, w_out_b, DMODEL*DINNER);
        gemm_glds64<64, float, false><<<dim3(LSEQ/128, DMODEL/64), blk, 0, stream>>>(
            xz + DINNER, 2*DINNER, w_out_b, DINNER, out, DMODEL, DINNER, nullptr);
    } else {
        // fallback tiers: R4 layout (in-place conv + serial scan, fp32-B gemms)
        bf16* xdbl = (bf16*)p; p += SZ_XDBL;
        size_t used = (size_t)(p - (char*)d_ws);
        bool dlt_f32 = (ws_size - used) >= SZ_DLTF;

        gemm_bt<float, bf16, false><<<dim3(LSEQ/64, (2*DINNER)/64), blk, 0, stream>>>(
            hs, DMODEL, w_in, DMODEL, xz, 2*DINNER, LSEQ, 2*DINNER, DMODEL, nullptr);
        conv_silu_inplace<<<dim3(DINNER/256), blk, 0, stream>>>(xz, w_conv);
        gemm_bt<bf16, bf16, false><<<dim3(LSEQ/64, 3), blk, 0, stream>>>(
            xz, 2*DINNER, w_xproj, DINNER, xdbl, DXP, LSEQ, DXP, DINNER, nullptr);
        if (dlt_f32) {
            float* dlt = (float*)p;
            gemm_bt<bf16, float, true><<<dim3(LSEQ/64, DINNER/64), blk, 0, stream>>>(
                xdbl, DXP, w_dt, DTRANK, dlt, DINNER, LSEQ, DINNER, DTRANK, b_dt);
            scan_serial<float><<<dim3(DINNER/64), blk, 0, stream>>>(dlt, xz, xdbl, A_log, Dp);
        } else {
            bf16* dlt = (bf16*)p;
            gemm_bt<bf16, bf16, true><<<dim3(LSEQ/64, DINNER/64), blk, 0, stream>>>(
                xdbl, DXP, w_dt, DTRANK, dlt, DINNER, LSEQ, DINNER, DTRANK, b_dt);
            scan_serial<bf16><<<dim3(DINNER/64), blk, 0, stream>>>(dlt, xz, xdbl, A_log, Dp);
        }
        gemm_bt<bf16, float, false><<<dim3(LSEQ/64, DMODEL/64), blk, 0, stream>>>(
            xz + DINNER, 2*DINNER, w_out, DINNER, out, DMODEL, LSEQ, DMODEL, DINNER, nullptr);
    }
}